// Round 5
// baseline (615.833 us; speedup 1.0000x reference)
//
#include <hip/hip_runtime.h>
#include <hip/hip_bf16.h>

#define B_N 4
#define C_N 512
#define F_N 4
#define HW_N 784
#define PL (F_N * HW_N)        // 3136 per (b,c) plane
#define NTOT 12544             // 16 * 784 columns
#define SCALE_F 0.125f

typedef unsigned short u16;
typedef __attribute__((ext_vector_type(8))) short bf16x8;
typedef __attribute__((ext_vector_type(4))) float f32x4;
typedef __attribute__((ext_vector_type(16))) float f32x16;
typedef __attribute__((ext_vector_type(8))) unsigned short ushort8;

__device__ __forceinline__ u16 f2b(float x) {
  unsigned u = __float_as_uint(x);
  unsigned r = ((u >> 16) & 1u) + 0x7fffu;
  return (u16)((u + r) >> 16);
}
__device__ __forceinline__ float b2f(u16 u) {
  return __uint_as_float(((unsigned)u) << 16);
}

typedef const __attribute__((address_space(1))) unsigned int* gas_ptr;
typedef __attribute__((address_space(3))) unsigned int* las_ptr;
__device__ __forceinline__ void gl_lds16(const void* g, void* l) {
  __builtin_amdgcn_global_load_lds((gas_ptr)(unsigned long long)(g),
                                   (las_ptr)(unsigned)(unsigned long long)(l),
                                   16, 0, 0);
}

// ---------------- zero small pad buffer ----------------
__global__ void zerok(float* z) { z[blockIdx.x * 256 + threadIdx.x] = 0.f; }

// ---------------- weight pack: [co][ci][TAPS] f32 -> [tap][co][ci] bf16 ----
template<int TAPS>
__global__ __launch_bounds__(256) void pack_w(const float* __restrict__ w,
                                              u16* __restrict__ wb, int ntot) {
  int o = blockIdx.x * 256 + threadIdx.x;
  if (o >= ntot) return;
  int tap = o / (C_N * C_N);
  int rem = o - tap * (C_N * C_N);          // co*512 + ci
  wb[o] = f2b(w[(size_t)rem * TAPS + tap]);
}

// ---------------- cast+transpose: x f32 NCDHW -> xt bf16 [bf*784+s][512] ----
__global__ __launch_bounds__(256) void cast_transpose(const float* __restrict__ x,
                                                      u16* __restrict__ xt) {
  const int bf = blockIdx.x, st = blockIdx.y, ct = blockIdx.z;
  const int b = bf >> 2, f = bf & 3;
  const int s0 = st * 64, c0 = ct * 64;
  const int tx = threadIdx.x & 63, ty = threadIdx.x >> 6;
  __shared__ float tile[64][65];
  const float* src = x + ((size_t)(b * C_N + c0)) * PL + (size_t)f * HW_N + s0;
  #pragma unroll
  for (int i = 0; i < 16; ++i) {
    int c = ty + i * 4;
    float v = 0.f;
    if (s0 + tx < HW_N) v = src[(size_t)c * PL + tx];
    tile[c][tx] = v;
  }
  __syncthreads();
  #pragma unroll
  for (int i = 0; i < 16; ++i) {
    int srow = ty + i * 4;
    int ss = s0 + srow;
    if (ss < HW_N) xt[((size_t)bf * HW_N + ss) * C_N + c0 + tx] = f2b(tile[tx][srow]);
  }
}

// ---------------- MFMA 32x32x16 implicit-GEMM conv (single weight) ----------
// xin: bf16 channels-last [12544][512]; wb: bf16 [TAPS][512][512]
// OUTM=1: bf16 channels-last; OUTM=2: bf16 planar [b][co][f][s]
template<int TAPS, int OUTM>
__global__ __launch_bounds__(256, 3) void conv_mfma32(
    const u16* __restrict__ xin, const u16* __restrict__ wb,
    u16* __restrict__ outp, const u16* __restrict__ zbuf)
{
  const int nt = blockIdx.x;       // 98
  const int cot = blockIdx.y;      // 4
  const int cobase = cot << 7;
  const int t = threadIdx.x;
  const int wv = t >> 6, l = t & 63;
  const int wm = wv >> 1, wn = wv & 1;
  const int l31 = l & 31, lk2 = l >> 5;

  __shared__ u16 Xs[128 * 64];
  __shared__ u16 Ws[128 * 64];

  const int crow = l >> 3;
  const int chunk = (l & 7) ^ (crow & 7);

  int gcol[4], sy[4], sx[4], sf[4];
  #pragma unroll
  for (int i = 0; i < 4; ++i) {
    gcol[i] = nt * 128 + wv * 32 + i * 8 + crow;
    int s = gcol[i] % HW_N;
    sy[i] = s / 28; sx[i] = s - (s / 28) * 28;
    sf[i] = (gcol[i] / HW_N) & 3;
  }

  f32x16 acc[2][2];
  #pragma unroll
  for (int fm = 0; fm < 2; ++fm)
    #pragma unroll
    for (int fn = 0; fn < 2; ++fn)
      #pragma unroll
      for (int e = 0; e < 16; ++e) acc[fm][fn][e] = 0.f;

  for (int tap = 0; tap < TAPS; ++tap) {
    const u16* xp[4];
    const u16* wp[4];
    int dy = 0, dx = 0, off;
    if (TAPS == 9) { dy = tap / 3; dx = tap - dy * 3; off = (dy - 1) * 28 + (dx - 1); }
    else           { off = (tap - 1) * HW_N; }
    #pragma unroll
    for (int i = 0; i < 4; ++i) {
      bool valid;
      if (TAPS == 9) {
        int yy = sy[i] + dy - 1, xx = sx[i] + dx - 1;
        valid = ((unsigned)yy < 28u) && ((unsigned)xx < 28u);
      } else {
        int ff = sf[i] + tap - 1;
        valid = ((unsigned)ff < 4u);
      }
      xp[i] = valid ? (xin + (size_t)(gcol[i] + off) * C_N + chunk * 8)
                    : (zbuf + chunk * 8);
      int co = cobase + wv * 32 + i * 8 + crow;
      wp[i] = wb + ((size_t)tap * C_N + co) * C_N + chunk * 8;
    }
    for (int kb = 0; kb < 8; ++kb) {
      __syncthreads();
      #pragma unroll
      for (int i = 0; i < 4; ++i) {
        gl_lds16(xp[i], (void*)(Xs + (wv * 4 + i) * 512));
        gl_lds16(wp[i], (void*)(Ws + (wv * 4 + i) * 512));
        xp[i] += 64; wp[i] += 64;
      }
      __syncthreads();
      #pragma unroll
      for (int kc = 0; kc < 4; ++kc) {
        const int slot = (kc * 2 + lk2) ^ (l31 & 7);
        bf16x8 af[2], bx[2];
        #pragma unroll
        for (int fm = 0; fm < 2; ++fm)
          af[fm] = *(const bf16x8*)&Ws[(wm * 64 + fm * 32 + l31) * 64 + slot * 8];
        #pragma unroll
        for (int fn = 0; fn < 2; ++fn)
          bx[fn] = *(const bf16x8*)&Xs[(wn * 64 + fn * 32 + l31) * 64 + slot * 8];
        #pragma unroll
        for (int fm = 0; fm < 2; ++fm)
          #pragma unroll
          for (int fn = 0; fn < 2; ++fn)
            acc[fm][fn] = __builtin_amdgcn_mfma_f32_32x32x16_bf16(
                af[fm], bx[fn], acc[fm][fn], 0, 0, 0);
      }
    }
  }

  // C layout (32x32): col=lane&31 (n), row=(reg&3)+8*(reg>>2)+4*(lane>>5) (co)
  #pragma unroll
  for (int fn = 0; fn < 2; ++fn) {
    int n = nt * 128 + wn * 64 + fn * 32 + l31;
    if (OUTM == 1) {
      #pragma unroll
      for (int fm = 0; fm < 2; ++fm) {
        int cob = cobase + wm * 64 + fm * 32 + lk2 * 4;
        #pragma unroll
        for (int rg = 0; rg < 4; ++rg) {
          ushort4 pk;
          pk.x = f2b(acc[fm][fn][rg * 4 + 0]);
          pk.y = f2b(acc[fm][fn][rg * 4 + 1]);
          pk.z = f2b(acc[fm][fn][rg * 4 + 2]);
          pk.w = f2b(acc[fm][fn][rg * 4 + 3]);
          *(ushort4*)&outp[(size_t)n * C_N + cob + rg * 8] = pk;
        }
      }
    } else {
      int bf = n / HW_N, s = n - (n / HW_N) * HW_N;
      int b = bf >> 2, f = bf & 3;
      #pragma unroll
      for (int fm = 0; fm < 2; ++fm) {
        int cob = cobase + wm * 64 + fm * 32 + lk2 * 4;
        #pragma unroll
        for (int rg = 0; rg < 4; ++rg)
          #pragma unroll
          for (int j = 0; j < 4; ++j) {
            int co = cob + rg * 8 + j;
            outp[((size_t)(b * C_N + co)) * PL + (size_t)f * HW_N + s] =
                f2b(acc[fm][fn][rg * 4 + j]);
          }
      }
    }
  }
}

// ---------------- dual-output conv311: k and v1 share X staging ------------
__global__ __launch_bounds__(256, 2) void conv311_dual(
    const u16* __restrict__ xin, const u16* __restrict__ wa,
    const u16* __restrict__ wc, u16* __restrict__ outa,
    u16* __restrict__ outc, const u16* __restrict__ zbuf)
{
  const int nt = blockIdx.x;       // 98
  const int cot = blockIdx.y;      // 4
  const int cobase = cot << 7;
  const int t = threadIdx.x;
  const int wv = t >> 6, l = t & 63;
  const int wm = wv >> 1, wn = wv & 1;
  const int l31 = l & 31, lk2 = l >> 5;

  __shared__ u16 Xs[128 * 64];
  __shared__ u16 Was[128 * 64];
  __shared__ u16 Wcs[128 * 64];

  const int crow = l >> 3;
  const int chunk = (l & 7) ^ (crow & 7);

  int gcol[4], sf[4];
  #pragma unroll
  for (int i = 0; i < 4; ++i) {
    gcol[i] = nt * 128 + wv * 32 + i * 8 + crow;
    sf[i] = (gcol[i] / HW_N) & 3;
  }

  f32x16 acca[2][2], accc[2][2];
  #pragma unroll
  for (int fm = 0; fm < 2; ++fm)
    #pragma unroll
    for (int fn = 0; fn < 2; ++fn)
      #pragma unroll
      for (int e = 0; e < 16; ++e) { acca[fm][fn][e] = 0.f; accc[fm][fn][e] = 0.f; }

  for (int tap = 0; tap < 3; ++tap) {
    const u16* xp[4];
    const u16* wpa[4];
    const u16* wpc[4];
    int off = (tap - 1) * HW_N;
    #pragma unroll
    for (int i = 0; i < 4; ++i) {
      int ff = sf[i] + tap - 1;
      bool valid = ((unsigned)ff < 4u);
      xp[i] = valid ? (xin + (size_t)(gcol[i] + off) * C_N + chunk * 8)
                    : (zbuf + chunk * 8);
      int co = cobase + wv * 32 + i * 8 + crow;
      wpa[i] = wa + ((size_t)tap * C_N + co) * C_N + chunk * 8;
      wpc[i] = wc + ((size_t)tap * C_N + co) * C_N + chunk * 8;
    }
    for (int kb = 0; kb < 8; ++kb) {
      __syncthreads();
      #pragma unroll
      for (int i = 0; i < 4; ++i) {
        gl_lds16(xp[i],  (void*)(Xs  + (wv * 4 + i) * 512));
        gl_lds16(wpa[i], (void*)(Was + (wv * 4 + i) * 512));
        gl_lds16(wpc[i], (void*)(Wcs + (wv * 4 + i) * 512));
        xp[i] += 64; wpa[i] += 64; wpc[i] += 64;
      }
      __syncthreads();
      #pragma unroll
      for (int kc = 0; kc < 4; ++kc) {
        const int slot = (kc * 2 + lk2) ^ (l31 & 7);
        bf16x8 afa[2], afc[2], bx[2];
        #pragma unroll
        for (int fm = 0; fm < 2; ++fm) {
          afa[fm] = *(const bf16x8*)&Was[(wm * 64 + fm * 32 + l31) * 64 + slot * 8];
          afc[fm] = *(const bf16x8*)&Wcs[(wm * 64 + fm * 32 + l31) * 64 + slot * 8];
        }
        #pragma unroll
        for (int fn = 0; fn < 2; ++fn)
          bx[fn] = *(const bf16x8*)&Xs[(wn * 64 + fn * 32 + l31) * 64 + slot * 8];
        #pragma unroll
        for (int fm = 0; fm < 2; ++fm)
          #pragma unroll
          for (int fn = 0; fn < 2; ++fn) {
            acca[fm][fn] = __builtin_amdgcn_mfma_f32_32x32x16_bf16(
                afa[fm], bx[fn], acca[fm][fn], 0, 0, 0);
            accc[fm][fn] = __builtin_amdgcn_mfma_f32_32x32x16_bf16(
                afc[fm], bx[fn], accc[fm][fn], 0, 0, 0);
          }
      }
    }
  }

  #pragma unroll
  for (int fn = 0; fn < 2; ++fn) {
    int n = nt * 128 + wn * 64 + fn * 32 + l31;
    #pragma unroll
    for (int fm = 0; fm < 2; ++fm) {
      int cob = cobase + wm * 64 + fm * 32 + lk2 * 4;
      #pragma unroll
      for (int rg = 0; rg < 4; ++rg) {
        ushort4 pa, pc;
        pa.x = f2b(acca[fm][fn][rg * 4 + 0]); pa.y = f2b(acca[fm][fn][rg * 4 + 1]);
        pa.z = f2b(acca[fm][fn][rg * 4 + 2]); pa.w = f2b(acca[fm][fn][rg * 4 + 3]);
        pc.x = f2b(accc[fm][fn][rg * 4 + 0]); pc.y = f2b(accc[fm][fn][rg * 4 + 1]);
        pc.z = f2b(accc[fm][fn][rg * 4 + 2]); pc.w = f2b(accc[fm][fn][rg * 4 + 3]);
        *(ushort4*)&outa[(size_t)n * C_N + cob + rg * 8] = pa;
        *(ushort4*)&outc[(size_t)n * C_N + cob + rg * 8] = pc;
      }
    }
  }
}

// ---------------- MFMA fused attention ----------------
__global__ __launch_bounds__(256, 4) void attn_mfma(
    const u16* __restrict__ q0, const u16* __restrict__ k0,
    const u16* __restrict__ v0,
    const float* __restrict__ rel_h, const float* __restrict__ rel_w,
    const float* __restrict__ rel_t, const float* __restrict__ rel_h2,
    const float* __restrict__ rel_w2, const float* __restrict__ rel_t2,
    float* __restrict__ out)
{
  // XCD-affine decode: all 7 q-tiles of a group land on one XCD (bid%8 const)
  const int bid = blockIdx.x;            // 896
  const int xcd = bid & 7, r = bid >> 3; // r 0..111
  const int gi = r / 7, qt = r - gi * 7;
  const int g = gi * 8 + xcd;
  const int b = g >> 5, gg = g & 31;
  const int cbase = gg << 4, h = gg >> 2, fgrp = gg & 3;
  const int qbase = min(qt * 128, 656);
  const int t = threadIdx.x;
  const int w = t >> 6, lane = t & 63, ll = lane & 15, lh = lane >> 4;

  __shared__ __align__(16) u16 smem[20480];        // 40 KB
  u16* Bp = smem;                                  // [64 k][128 d] swz
  u16* Vt = smem + 8192;                           // [64 e][64 k] swz
  u16* Pm = smem + 12288;                          // [128 q][64 k] swz
  float* Obuf = (float*)smem;                      // [64 e][130 q] (epilogue)

  const size_t slab = ((size_t)b * C_N + cbase) * PL;

  bf16x8 afr[2][4];
  #pragma unroll
  for (int mf = 0; mf < 2; ++mf) {
    const int q = qbase + w * 32 + mf * 16 + ll;
    const int y = q / 28, x = q - (q / 28) * 28;
    #pragma unroll
    for (int kk = 0; kk < 2; ++kk) {
      int c = kk * 4 + lh;
      afr[mf][kk] = *(const bf16x8*)&q0[((size_t)((b * 4 + (c >> 1)) * HW_N + q)) * C_N
                                        + cbase + (c & 1) * 8];
    }
    #pragma unroll
    for (int kk = 0; kk < 2; ++kk) {
      int ebase = kk * 32 + lh * 8;
      bf16x8 pv;
      #pragma unroll
      for (int j = 0; j < 8; ++j) {
        int e = ebase + j;
        int di = (e & 15) * 4 + (e >> 4);
        int idx = h * 64 + di;
        pv[j] = (short)f2b(rel_h[idx * 28 + y] + rel_w[idx * 28 + x]
                           + rel_t[idx * 4 + fgrp]);
      }
      afr[mf][2 + kk] = pv;
    }
  }

  f32x4 oacc[2][4];
  float m_[2][4], l_[2][4];
  #pragma unroll
  for (int mf = 0; mf < 2; ++mf)
    #pragma unroll
    for (int r2 = 0; r2 < 4; ++r2) { m_[mf][r2] = -1e30f; l_[mf][r2] = 0.f; }
  #pragma unroll
  for (int mf = 0; mf < 2; ++mf)
    #pragma unroll
    for (int nf = 0; nf < 4; ++nf) oacc[mf][nf] = (f32x4){0.f, 0.f, 0.f, 0.f};

  for (int kt = 0; kt < 13; ++kt) {
    const int kbase = kt * 64;
    __syncthreads();
    #pragma unroll
    for (int i = 0; i < 4; ++i) {
      int krow = w * 16 + i * 4 + lh;
      int c = (ll & 8) | ((ll ^ krow) & 7);
      int cc = c & 7;
      const u16* base = (c < 8) ? k0 : q0;
      const u16* src = base + ((size_t)((b * 4 + (cc >> 1)) * HW_N + kbase + krow)) * C_N
                       + cbase + (cc & 1) * 8;
      gl_lds16(src, (void*)(Bp + (w * 16 + i * 4) * 128));
    }
    #pragma unroll
    for (int i = 0; i < 2; ++i) {
      int e = w * 16 + i * 8 + (lane >> 3);
      int ch = (lane & 7) ^ (e & 7);
      int di = (e & 15) * 4 + (e >> 4);
      const u16* src = v0 + slab + (size_t)di * HW_N + kbase + ch * 8;
      gl_lds16(src, (void*)(Vt + (w * 16 + i * 8) * 64));
    }
    __syncthreads();

    f32x4 sacc[2][4];
    #pragma unroll
    for (int mf = 0; mf < 2; ++mf)
      #pragma unroll
      for (int nf = 0; nf < 4; ++nf) sacc[mf][nf] = (f32x4){0.f, 0.f, 0.f, 0.f};
    #pragma unroll
    for (int kk = 0; kk < 4; ++kk) {
      bf16x8 bx[4];
      #pragma unroll
      for (int nf = 0; nf < 4; ++nf) {
        int slot = (kk * 4 + lh) ^ (ll & 7);
        bx[nf] = *(const bf16x8*)&Bp[(nf * 16 + ll) * 128 + slot * 8];
      }
      #pragma unroll
      for (int mf = 0; mf < 2; ++mf)
        #pragma unroll
        for (int nf = 0; nf < 4; ++nf)
          sacc[mf][nf] = __builtin_amdgcn_mfma_f32_16x16x32_bf16(
              afr[mf][kk], bx[nf], sacc[mf][nf], 0, 0, 0);
    }

    bool kval[4];
    #pragma unroll
    for (int nf = 0; nf < 4; ++nf) kval[nf] = (kbase + nf * 16 + ll) < HW_N;
    #pragma unroll
    for (int mf = 0; mf < 2; ++mf) {
      const int qlb = w * 32 + mf * 16;
      #pragma unroll
      for (int r2 = 0; r2 < 4; ++r2) {
        float s0 = kval[0] ? sacc[mf][0][r2] * SCALE_F : -1e30f;
        float s1 = kval[1] ? sacc[mf][1][r2] * SCALE_F : -1e30f;
        float s2 = kval[2] ? sacc[mf][2][r2] * SCALE_F : -1e30f;
        float s3 = kval[3] ? sacc[mf][3][r2] * SCALE_F : -1e30f;
        float rmax = fmaxf(fmaxf(s0, s1), fmaxf(s2, s3));
        #pragma unroll
        for (int off = 8; off >= 1; off >>= 1)
          rmax = fmaxf(rmax, __shfl_xor(rmax, off));
        float mn = fmaxf(m_[mf][r2], rmax);
        float sc = __expf(m_[mf][r2] - mn);
        float p0 = __expf(s0 - mn), p1 = __expf(s1 - mn);
        float p2 = __expf(s2 - mn), p3 = __expf(s3 - mn);
        float psum = (p0 + p1) + (p2 + p3);
        #pragma unroll
        for (int off = 8; off >= 1; off >>= 1)
          psum += __shfl_xor(psum, off);
        l_[mf][r2] = l_[mf][r2] * sc + psum;
        m_[mf][r2] = mn;
        const int ql = qlb + lh * 4 + r2;
        const int swz = (ql & 7);
        Pm[ql * 64 + (((ll >> 3)       ^ swz) * 8) + (ll & 7)] = f2b(p0);
        Pm[ql * 64 + (((2 + (ll >> 3)) ^ swz) * 8) + (ll & 7)] = f2b(p1);
        Pm[ql * 64 + (((4 + (ll >> 3)) ^ swz) * 8) + (ll & 7)] = f2b(p2);
        Pm[ql * 64 + (((6 + (ll >> 3)) ^ swz) * 8) + (ll & 7)] = f2b(p3);
        #pragma unroll
        for (int nf = 0; nf < 4; ++nf) oacc[mf][nf][r2] *= sc;
      }
    }

    #pragma unroll
    for (int ks = 0; ks < 2; ++ks) {
      bf16x8 pa[2], vb[4];
      #pragma unroll
      for (int mf = 0; mf < 2; ++mf) {
        int ql = w * 32 + mf * 16 + ll;
        int slot = (ks * 4 + lh) ^ (ql & 7);
        pa[mf] = *(const bf16x8*)&Pm[ql * 64 + slot * 8];
      }
      #pragma unroll
      for (int nf = 0; nf < 4; ++nf) {
        int e = nf * 16 + ll;
        int slot = (ks * 4 + lh) ^ (e & 7);
        vb[nf] = *(const bf16x8*)&Vt[e * 64 + slot * 8];
      }
      #pragma unroll
      for (int mf = 0; mf < 2; ++mf)
        #pragma unroll
        for (int nf = 0; nf < 4; ++nf)
          oacc[mf][nf] = __builtin_amdgcn_mfma_f32_16x16x32_bf16(
              pa[mf], vb[nf], oacc[mf][nf], 0, 0, 0);
    }
  }

  __syncthreads();
  float rinv[2][4];
  #pragma unroll
  for (int mf = 0; mf < 2; ++mf)
    #pragma unroll
    for (int r2 = 0; r2 < 4; ++r2) rinv[mf][r2] = 1.f / l_[mf][r2];
  #pragma unroll
  for (int mf = 0; mf < 2; ++mf)
    #pragma unroll
    for (int nf = 0; nf < 4; ++nf)
      #pragma unroll
      for (int r2 = 0; r2 < 4; ++r2)
        Obuf[(nf * 16 + ll) * 130 + w * 32 + mf * 16 + lh * 4 + r2] =
            oacc[mf][nf][r2] * rinv[mf][r2];
  __syncthreads();
  #pragma unroll 4
  for (int j = 0; j < 32; ++j) {
    int idx = t + 256 * j;
    int e = idx >> 7, ql = idx & 127;
    int s = qbase + ql;
    int c = cbase + (e & 15), fr = e >> 4;
    int y = s / 28, x = s - (s / 28) * 28;
    out[(((size_t)(b * C_N + c)) * 4 + fr) * HW_N + s] =
        Obuf[e * 130 + ql] + rel_t2[c * 4 + fr] + rel_h2[c * 28 + y]
        + rel_w2[c * 28 + x];
  }
}

extern "C" void kernel_launch(void* const* d_in, const int* in_sizes, int n_in,
                              void* d_out, int out_size, void* d_ws, size_t ws_size,
                              hipStream_t stream) {
  const float* x     = (const float*)d_in[0];
  const float* Wq    = (const float*)d_in[1];
  const float* Wk    = (const float*)d_in[2];
  const float* Wv1   = (const float*)d_in[3];
  const float* Wv2   = (const float*)d_in[4];
  const float* relh  = (const float*)d_in[5];
  const float* relw  = (const float*)d_in[6];
  const float* relt  = (const float*)d_in[7];
  const float* relh2 = (const float*)d_in[8];
  const float* relw2 = (const float*)d_in[9];
  const float* relt2 = (const float*)d_in[10];
  float* out = (float*)d_out;
  char* ws = (char*)d_ws;

  const size_t NE = (size_t)NTOT * C_N;
  u16* xt   = (u16*)(ws);            // xt, then v0 (planar) after xt is dead
  u16* q0   = (u16*)(ws + NE * 2);   // q channels-last
  u16* t0   = (u16*)(ws + NE * 4);   // v1 = conv311(x, Wv1) channels-last
  u16* k0   = (u16*)(ws + NE * 6);   // k channels-last
  u16* wqb  = (u16*)(ws + NE * 8);
  u16* wkb  = (u16*)(ws + NE * 8 + 4718592);
  u16* wv1b = (u16*)(ws + NE * 8 + 4718592 + 1572864);
  u16* wv2b = (u16*)(ws + NE * 8 + 4718592 + 2 * 1572864);
  u16* zbuf = (u16*)(ws + NE * 8 + 2 * 4718592 + 2 * 1572864);

  zerok<<<dim3(4), dim3(256), 0, stream>>>((float*)zbuf);
  pack_w<9><<<dim3(9216), dim3(256), 0, stream>>>(Wq,  wqb,  9 * C_N * C_N);
  pack_w<3><<<dim3(3072), dim3(256), 0, stream>>>(Wk,  wkb,  3 * C_N * C_N);
  pack_w<3><<<dim3(3072), dim3(256), 0, stream>>>(Wv1, wv1b, 3 * C_N * C_N);
  pack_w<9><<<dim3(9216), dim3(256), 0, stream>>>(Wv2, wv2b, 9 * C_N * C_N);
  cast_transpose<<<dim3(16, 13, 8), dim3(256), 0, stream>>>(x, xt);

  dim3 cgrid(98, 4), blk(256);
  // k = conv311(x, Wk), v1 = conv311(x, Wv1)  (legal fusion: same input x)
  conv311_dual<<<cgrid, blk, 0, stream>>>(xt, wkb, wv1b, k0, t0, zbuf);
  // q = conv133(x, Wq) channels-last
  conv_mfma32<9, 1><<<cgrid, blk, 0, stream>>>(xt, wqb, q0, zbuf);
  // v = conv133(v1, Wv2) planar, into the now-dead xt slab  (reference order!)
  conv_mfma32<9, 2><<<cgrid, blk, 0, stream>>>(t0, wv2b, xt, zbuf);

  attn_mfma<<<dim3(896), blk, 0, stream>>>(
      q0, k0, xt, relh, relw, relt, relh2, relw2, relt2, out);
}

// Round 7
// 445.176 us; speedup vs baseline: 1.3833x; 1.3833x over previous
//
#include <hip/hip_runtime.h>
#include <hip/hip_bf16.h>

#define B_N 4
#define C_N 512
#define F_N 4
#define HW_N 784
#define PL (F_N * HW_N)        // 3136 per (b,c) plane
#define NTOT 12544             // 16 * 784 columns
#define SCALE_F 0.125f

typedef unsigned short u16;
typedef __attribute__((ext_vector_type(8))) short bf16x8;
typedef __attribute__((ext_vector_type(4))) float f32x4;
typedef __attribute__((ext_vector_type(16))) float f32x16;
typedef __attribute__((ext_vector_type(8))) unsigned short ushort8;

__device__ __forceinline__ u16 f2b(float x) {
  unsigned u = __float_as_uint(x);
  unsigned r = ((u >> 16) & 1u) + 0x7fffu;
  return (u16)((u + r) >> 16);
}
__device__ __forceinline__ float b2f(u16 u) {
  return __uint_as_float(((unsigned)u) << 16);
}

typedef const __attribute__((address_space(1))) unsigned int* gas_ptr;
typedef __attribute__((address_space(3))) unsigned int* las_ptr;
__device__ __forceinline__ void gl_lds16(const void* g, void* l) {
  __builtin_amdgcn_global_load_lds((gas_ptr)(unsigned long long)(g),
                                   (las_ptr)(unsigned)(unsigned long long)(l),
                                   16, 0, 0);
}

// ---------------- zero small pad buffer ----------------
__global__ void zerok(float* z) { z[blockIdx.x * 256 + threadIdx.x] = 0.f; }

// ---------------- weight pack: [co][ci][TAPS] f32 -> [tap][co][ci] bf16 ----
template<int TAPS>
__global__ __launch_bounds__(256) void pack_w(const float* __restrict__ w,
                                              u16* __restrict__ wb, int ntot) {
  int o = blockIdx.x * 256 + threadIdx.x;
  if (o >= ntot) return;
  int tap = o / (C_N * C_N);
  int rem = o - tap * (C_N * C_N);          // co*512 + ci
  wb[o] = f2b(w[(size_t)rem * TAPS + tap]);
}

// ---------------- cast+transpose: x f32 NCDHW -> xt bf16 [bf*784+s][512] ----
__global__ __launch_bounds__(256) void cast_transpose(const float* __restrict__ x,
                                                      u16* __restrict__ xt) {
  const int bf = blockIdx.x, st = blockIdx.y, ct = blockIdx.z;
  const int b = bf >> 2, f = bf & 3;
  const int s0 = st * 64, c0 = ct * 64;
  const int tx = threadIdx.x & 63, ty = threadIdx.x >> 6;
  __shared__ float tile[64][65];
  const float* src = x + ((size_t)(b * C_N + c0)) * PL + (size_t)f * HW_N + s0;
  #pragma unroll
  for (int i = 0; i < 16; ++i) {
    int c = ty + i * 4;
    float v = 0.f;
    if (s0 + tx < HW_N) v = src[(size_t)c * PL + tx];
    tile[c][tx] = v;
  }
  __syncthreads();
  #pragma unroll
  for (int i = 0; i < 16; ++i) {
    int srow = ty + i * 4;
    int ss = s0 + srow;
    if (ss < HW_N) xt[((size_t)bf * HW_N + ss) * C_N + c0 + tx] = f2b(tile[tx][srow]);
  }
}

// ---------------- MFMA 32x32x16 implicit-GEMM conv, double-buffered ---------
// xin: bf16 channels-last [12544][512]; wb: bf16 [TAPS][512][512]
// OUTM=1: bf16 channels-last; OUTM=2: bf16 planar [b][co][f][s]
// Pipeline: stage(next)->compute(cur)->barrier (T3 minimum 2-phase recipe).
template<int TAPS, int OUTM>
__global__ __launch_bounds__(256) void conv_mfma32(
    const u16* __restrict__ xin, const u16* __restrict__ wb,
    u16* __restrict__ outp, const u16* __restrict__ zbuf)
{
  const int nt = blockIdx.x;       // 98
  const int cot = blockIdx.y;      // 4
  const int cobase = cot << 7;
  const int t = threadIdx.x;
  const int wv = t >> 6, l = t & 63;
  const int wm = wv >> 1, wn = wv & 1;
  const int l31 = l & 31, lk2 = l >> 5;

  __shared__ u16 Xs[2][128 * 64];  // 32 KB
  __shared__ u16 Ws[2][128 * 64];  // 32 KB

  const int crow = l >> 3;
  const int chunk = (l & 7) ^ (crow & 7);

  int gcol[4], sy[4], sx[4], sf[4];
  const u16* xbase[4];
  const u16* wbase[4];
  #pragma unroll
  for (int i = 0; i < 4; ++i) {
    gcol[i] = nt * 128 + wv * 32 + i * 8 + crow;
    int s = gcol[i] % HW_N;
    sy[i] = s / 28; sx[i] = s - (s / 28) * 28;
    sf[i] = (gcol[i] / HW_N) & 3;
    xbase[i] = xin + (size_t)gcol[i] * C_N + chunk * 8;
    int co = cobase + wv * 32 + i * 8 + crow;
    wbase[i] = wb + (size_t)co * C_N + chunk * 8;
  }
  const u16* zsrc = zbuf + chunk * 8;

  f32x16 acc[2][2];
  #pragma unroll
  for (int fm = 0; fm < 2; ++fm)
    #pragma unroll
    for (int fn = 0; fn < 2; ++fn)
      #pragma unroll
      for (int e = 0; e < 16; ++e) acc[fm][fn][e] = 0.f;

  const int NIT = TAPS * 8;

  auto STAGE = [&](int idx, int sel) {
    int tap = idx >> 3, kb = idx & 7;
    int off, dy = 0, dx = 0;
    if (TAPS == 9) { dy = (tap * 11) >> 5; dx = tap - dy * 3;
                     off = (dy - 1) * 28 + (dx - 1); }
    else           { off = (tap - 1) * HW_N; }
    #pragma unroll
    for (int i = 0; i < 4; ++i) {
      bool valid;
      if (TAPS == 9) {
        int yy = sy[i] + dy - 1, xx = sx[i] + dx - 1;
        valid = ((unsigned)yy < 28u) && ((unsigned)xx < 28u);
      } else {
        int ff = sf[i] + tap - 1;
        valid = ((unsigned)ff < 4u);
      }
      const u16* sx_ = valid ? (xbase[i] + off * (int)C_N + kb * 64) : zsrc;
      const u16* sw_ = wbase[i] + tap * (C_N * C_N) + kb * 64;
      gl_lds16(sx_, (void*)(&Xs[sel][0] + (wv * 4 + i) * 512));
      gl_lds16(sw_, (void*)(&Ws[sel][0] + (wv * 4 + i) * 512));
    }
  };

  auto COMPUTE = [&](int sel) {
    #pragma unroll
    for (int kc = 0; kc < 4; ++kc) {
      const int slot = (kc * 2 + lk2) ^ (l31 & 7);
      bf16x8 af[2], bx[2];
      #pragma unroll
      for (int fm = 0; fm < 2; ++fm)
        af[fm] = *(const bf16x8*)&Ws[sel][(wm * 64 + fm * 32 + l31) * 64 + slot * 8];
      #pragma unroll
      for (int fn = 0; fn < 2; ++fn)
        bx[fn] = *(const bf16x8*)&Xs[sel][(wn * 64 + fn * 32 + l31) * 64 + slot * 8];
      #pragma unroll
      for (int fm = 0; fm < 2; ++fm)
        #pragma unroll
        for (int fn = 0; fn < 2; ++fn)
          acc[fm][fn] = __builtin_amdgcn_mfma_f32_32x32x16_bf16(
              af[fm], bx[fn], acc[fm][fn], 0, 0, 0);
    }
  };

  STAGE(0, 0);
  __syncthreads();                 // drains vmcnt(0): buf0 ready
  for (int base = 0; base < NIT; base += 2) {
    if (base + 1 < NIT) STAGE(base + 1, 1);
    COMPUTE(0);
    __syncthreads();               // buf1 ready; buf0 reads done
    if (base + 2 < NIT) STAGE(base + 2, 0);
    COMPUTE(1);
    __syncthreads();               // buf0 ready; buf1 reads done
  }

  // C layout (32x32): col=lane&31 (n), row=(reg&3)+8*(reg>>2)+4*(lane>>5) (co)
  #pragma unroll
  for (int fn = 0; fn < 2; ++fn) {
    int n = nt * 128 + wn * 64 + fn * 32 + l31;
    if (OUTM == 1) {
      #pragma unroll
      for (int fm = 0; fm < 2; ++fm) {
        int cob = cobase + wm * 64 + fm * 32 + lk2 * 4;
        #pragma unroll
        for (int rg = 0; rg < 4; ++rg) {
          ushort4 pk;
          pk.x = f2b(acc[fm][fn][rg * 4 + 0]);
          pk.y = f2b(acc[fm][fn][rg * 4 + 1]);
          pk.z = f2b(acc[fm][fn][rg * 4 + 2]);
          pk.w = f2b(acc[fm][fn][rg * 4 + 3]);
          *(ushort4*)&outp[(size_t)n * C_N + cob + rg * 8] = pk;
        }
      }
    } else {
      int bf = n / HW_N, s = n - (n / HW_N) * HW_N;
      int b = bf >> 2, f = bf & 3;
      #pragma unroll
      for (int fm = 0; fm < 2; ++fm) {
        int cob = cobase + wm * 64 + fm * 32 + lk2 * 4;
        #pragma unroll
        for (int rg = 0; rg < 4; ++rg)
          #pragma unroll
          for (int j = 0; j < 4; ++j) {
            int co = cob + rg * 8 + j;
            outp[((size_t)(b * C_N + co)) * PL + (size_t)f * HW_N + s] =
                f2b(acc[fm][fn][rg * 4 + j]);
          }
      }
    }
  }
}

// ---------------- dual-output conv311: k and v1 share X staging ------------
__global__ __launch_bounds__(256, 2) void conv311_dual(
    const u16* __restrict__ xin, const u16* __restrict__ wa,
    const u16* __restrict__ wc, u16* __restrict__ outa,
    u16* __restrict__ outc, const u16* __restrict__ zbuf)
{
  const int nt = blockIdx.x;       // 98
  const int cot = blockIdx.y;      // 4
  const int cobase = cot << 7;
  const int t = threadIdx.x;
  const int wv = t >> 6, l = t & 63;
  const int wm = wv >> 1, wn = wv & 1;
  const int l31 = l & 31, lk2 = l >> 5;

  __shared__ u16 Xs[128 * 64];
  __shared__ u16 Was[128 * 64];
  __shared__ u16 Wcs[128 * 64];

  const int crow = l >> 3;
  const int chunk = (l & 7) ^ (crow & 7);

  int gcol[4], sf[4];
  #pragma unroll
  for (int i = 0; i < 4; ++i) {
    gcol[i] = nt * 128 + wv * 32 + i * 8 + crow;
    sf[i] = (gcol[i] / HW_N) & 3;
  }

  f32x16 acca[2][2], accc[2][2];
  #pragma unroll
  for (int fm = 0; fm < 2; ++fm)
    #pragma unroll
    for (int fn = 0; fn < 2; ++fn)
      #pragma unroll
      for (int e = 0; e < 16; ++e) { acca[fm][fn][e] = 0.f; accc[fm][fn][e] = 0.f; }

  for (int tap = 0; tap < 3; ++tap) {
    const u16* xp[4];
    const u16* wpa[4];
    const u16* wpc[4];
    int off = (tap - 1) * HW_N;
    #pragma unroll
    for (int i = 0; i < 4; ++i) {
      int ff = sf[i] + tap - 1;
      bool valid = ((unsigned)ff < 4u);
      xp[i] = valid ? (xin + (size_t)(gcol[i] + off) * C_N + chunk * 8)
                    : (zbuf + chunk * 8);
      int co = cobase + wv * 32 + i * 8 + crow;
      wpa[i] = wa + ((size_t)tap * C_N + co) * C_N + chunk * 8;
      wpc[i] = wc + ((size_t)tap * C_N + co) * C_N + chunk * 8;
    }
    for (int kb = 0; kb < 8; ++kb) {
      __syncthreads();
      #pragma unroll
      for (int i = 0; i < 4; ++i) {
        gl_lds16(xp[i],  (void*)(Xs  + (wv * 4 + i) * 512));
        gl_lds16(wpa[i], (void*)(Was + (wv * 4 + i) * 512));
        gl_lds16(wpc[i], (void*)(Wcs + (wv * 4 + i) * 512));
        xp[i] += 64; wpa[i] += 64; wpc[i] += 64;
      }
      __syncthreads();
      #pragma unroll
      for (int kc = 0; kc < 4; ++kc) {
        const int slot = (kc * 2 + lk2) ^ (l31 & 7);
        bf16x8 afa[2], afc[2], bx[2];
        #pragma unroll
        for (int fm = 0; fm < 2; ++fm) {
          afa[fm] = *(const bf16x8*)&Was[(wm * 64 + fm * 32 + l31) * 64 + slot * 8];
          afc[fm] = *(const bf16x8*)&Wcs[(wm * 64 + fm * 32 + l31) * 64 + slot * 8];
        }
        #pragma unroll
        for (int fn = 0; fn < 2; ++fn)
          bx[fn] = *(const bf16x8*)&Xs[(wn * 64 + fn * 32 + l31) * 64 + slot * 8];
        #pragma unroll
        for (int fm = 0; fm < 2; ++fm)
          #pragma unroll
          for (int fn = 0; fn < 2; ++fn) {
            acca[fm][fn] = __builtin_amdgcn_mfma_f32_32x32x16_bf16(
                afa[fm], bx[fn], acca[fm][fn], 0, 0, 0);
            accc[fm][fn] = __builtin_amdgcn_mfma_f32_32x32x16_bf16(
                afc[fm], bx[fn], accc[fm][fn], 0, 0, 0);
          }
      }
    }
  }

  #pragma unroll
  for (int fn = 0; fn < 2; ++fn) {
    int n = nt * 128 + wn * 64 + fn * 32 + l31;
    #pragma unroll
    for (int fm = 0; fm < 2; ++fm) {
      int cob = cobase + wm * 64 + fm * 32 + lk2 * 4;
      #pragma unroll
      for (int rg = 0; rg < 4; ++rg) {
        ushort4 pa, pc;
        pa.x = f2b(acca[fm][fn][rg * 4 + 0]); pa.y = f2b(acca[fm][fn][rg * 4 + 1]);
        pa.z = f2b(acca[fm][fn][rg * 4 + 2]); pa.w = f2b(acca[fm][fn][rg * 4 + 3]);
        pc.x = f2b(accc[fm][fn][rg * 4 + 0]); pc.y = f2b(accc[fm][fn][rg * 4 + 1]);
        pc.z = f2b(accc[fm][fn][rg * 4 + 2]); pc.w = f2b(accc[fm][fn][rg * 4 + 3]);
        *(ushort4*)&outa[(size_t)n * C_N + cob + rg * 8] = pa;
        *(ushort4*)&outc[(size_t)n * C_N + cob + rg * 8] = pc;
      }
    }
  }
}

// ---------------- MFMA fused attention ----------------
__global__ __launch_bounds__(256, 2) void attn_mfma(
    const u16* __restrict__ q0, const u16* __restrict__ k0,
    const u16* __restrict__ v0,
    const float* __restrict__ rel_h, const float* __restrict__ rel_w,
    const float* __restrict__ rel_t, const float* __restrict__ rel_h2,
    const float* __restrict__ rel_w2, const float* __restrict__ rel_t2,
    float* __restrict__ out)
{
  // XCD-affine decode: all 7 q-tiles of a group land on one XCD (bid%8 const)
  const int bid = blockIdx.x;            // 896
  const int xcd = bid & 7, r = bid >> 3; // r 0..111
  const int gi = r / 7, qt = r - gi * 7;
  const int g = gi * 8 + xcd;
  const int b = g >> 5, gg = g & 31;
  const int cbase = gg << 4, h = gg >> 2, fgrp = gg & 3;
  const int qbase = min(qt * 128, 656);
  const int t = threadIdx.x;
  const int w = t >> 6, lane = t & 63, ll = lane & 15, lh = lane >> 4;

  __shared__ __align__(16) u16 smem[20480];        // 40 KB
  u16* Bp = smem;                                  // [64 k][128 d] swz
  u16* Vt = smem + 8192;                           // [64 e][64 k] swz
  u16* Pm = smem + 12288;                          // [128 q][64 k] swz
  float* Obuf = (float*)smem;                      // [64 e][130 q] (epilogue)

  const size_t slab = ((size_t)b * C_N + cbase) * PL;

  bf16x8 afr[2][4];
  #pragma unroll
  for (int mf = 0; mf < 2; ++mf) {
    const int q = qbase + w * 32 + mf * 16 + ll;
    const int y = q / 28, x = q - (q / 28) * 28;
    #pragma unroll
    for (int kk = 0; kk < 2; ++kk) {
      int c = kk * 4 + lh;
      afr[mf][kk] = *(const bf16x8*)&q0[((size_t)((b * 4 + (c >> 1)) * HW_N + q)) * C_N
                                        + cbase + (c & 1) * 8];
    }
    #pragma unroll
    for (int kk = 0; kk < 2; ++kk) {
      int ebase = kk * 32 + lh * 8;
      bf16x8 pv;
      #pragma unroll
      for (int j = 0; j < 8; ++j) {
        int e = ebase + j;
        int di = (e & 15) * 4 + (e >> 4);
        int idx = h * 64 + di;
        pv[j] = (short)f2b(rel_h[idx * 28 + y] + rel_w[idx * 28 + x]
                           + rel_t[idx * 4 + fgrp]);
      }
      afr[mf][2 + kk] = pv;
    }
  }

  f32x4 oacc[2][4];
  float m_[2][4], l_[2][4];
  #pragma unroll
  for (int mf = 0; mf < 2; ++mf)
    #pragma unroll
    for (int r2 = 0; r2 < 4; ++r2) { m_[mf][r2] = -1e30f; l_[mf][r2] = 0.f; }
  #pragma unroll
  for (int mf = 0; mf < 2; ++mf)
    #pragma unroll
    for (int nf = 0; nf < 4; ++nf) oacc[mf][nf] = (f32x4){0.f, 0.f, 0.f, 0.f};

  for (int kt = 0; kt < 13; ++kt) {
    const int kbase = kt * 64;
    __syncthreads();
    #pragma unroll
    for (int i = 0; i < 4; ++i) {
      int krow = w * 16 + i * 4 + lh;
      int c = (ll & 8) | ((ll ^ krow) & 7);
      int cc = c & 7;
      const u16* base = (c < 8) ? k0 : q0;
      const u16* src = base + ((size_t)((b * 4 + (cc >> 1)) * HW_N + kbase + krow)) * C_N
                       + cbase + (cc & 1) * 8;
      gl_lds16(src, (void*)(Bp + (w * 16 + i * 4) * 128));
    }
    #pragma unroll
    for (int i = 0; i < 2; ++i) {
      int e = w * 16 + i * 8 + (lane >> 3);
      int ch = (lane & 7) ^ (e & 7);
      int di = (e & 15) * 4 + (e >> 4);
      const u16* src = v0 + slab + (size_t)di * HW_N + kbase + ch * 8;
      gl_lds16(src, (void*)(Vt + (w * 16 + i * 8) * 64));
    }
    __syncthreads();

    f32x4 sacc[2][4];
    #pragma unroll
    for (int mf = 0; mf < 2; ++mf)
      #pragma unroll
      for (int nf = 0; nf < 4; ++nf) sacc[mf][nf] = (f32x4){0.f, 0.f, 0.f, 0.f};
    #pragma unroll
    for (int kk = 0; kk < 4; ++kk) {
      bf16x8 bx[4];
      #pragma unroll
      for (int nf = 0; nf < 4; ++nf) {
        int slot = (kk * 4 + lh) ^ (ll & 7);
        bx[nf] = *(const bf16x8*)&Bp[(nf * 16 + ll) * 128 + slot * 8];
      }
      #pragma unroll
      for (int mf = 0; mf < 2; ++mf)
        #pragma unroll
        for (int nf = 0; nf < 4; ++nf)
          sacc[mf][nf] = __builtin_amdgcn_mfma_f32_16x16x32_bf16(
              afr[mf][kk], bx[nf], sacc[mf][nf], 0, 0, 0);
    }

    bool kval[4];
    #pragma unroll
    for (int nf = 0; nf < 4; ++nf) kval[nf] = (kbase + nf * 16 + ll) < HW_N;
    #pragma unroll
    for (int mf = 0; mf < 2; ++mf) {
      const int qlb = w * 32 + mf * 16;
      #pragma unroll
      for (int r2 = 0; r2 < 4; ++r2) {
        float s0 = kval[0] ? sacc[mf][0][r2] * SCALE_F : -1e30f;
        float s1 = kval[1] ? sacc[mf][1][r2] * SCALE_F : -1e30f;
        float s2 = kval[2] ? sacc[mf][2][r2] * SCALE_F : -1e30f;
        float s3 = kval[3] ? sacc[mf][3][r2] * SCALE_F : -1e30f;
        float rmax = fmaxf(fmaxf(s0, s1), fmaxf(s2, s3));
        #pragma unroll
        for (int off = 8; off >= 1; off >>= 1)
          rmax = fmaxf(rmax, __shfl_xor(rmax, off));
        float mn = fmaxf(m_[mf][r2], rmax);
        float sc = __expf(m_[mf][r2] - mn);
        float p0 = __expf(s0 - mn), p1 = __expf(s1 - mn);
        float p2 = __expf(s2 - mn), p3 = __expf(s3 - mn);
        float psum = (p0 + p1) + (p2 + p3);
        #pragma unroll
        for (int off = 8; off >= 1; off >>= 1)
          psum += __shfl_xor(psum, off);
        l_[mf][r2] = l_[mf][r2] * sc + psum;
        m_[mf][r2] = mn;
        const int ql = qlb + lh * 4 + r2;
        const int swz = (ql & 7);
        Pm[ql * 64 + (((ll >> 3)       ^ swz) * 8) + (ll & 7)] = f2b(p0);
        Pm[ql * 64 + (((2 + (ll >> 3)) ^ swz) * 8) + (ll & 7)] = f2b(p1);
        Pm[ql * 64 + (((4 + (ll >> 3)) ^ swz) * 8) + (ll & 7)] = f2b(p2);
        Pm[ql * 64 + (((6 + (ll >> 3)) ^ swz) * 8) + (ll & 7)] = f2b(p3);
        #pragma unroll
        for (int nf = 0; nf < 4; ++nf) oacc[mf][nf][r2] *= sc;
      }
    }

    #pragma unroll
    for (int ks = 0; ks < 2; ++ks) {
      bf16x8 pa[2], vb[4];
      #pragma unroll
      for (int mf = 0; mf < 2; ++mf) {
        int ql = w * 32 + mf * 16 + ll;
        int slot = (ks * 4 + lh) ^ (ql & 7);
        pa[mf] = *(const bf16x8*)&Pm[ql * 64 + slot * 8];
      }
      #pragma unroll
      for (int nf = 0; nf < 4; ++nf) {
        int e = nf * 16 + ll;
        int slot = (ks * 4 + lh) ^ (e & 7);
        vb[nf] = *(const bf16x8*)&Vt[e * 64 + slot * 8];
      }
      #pragma unroll
      for (int mf = 0; mf < 2; ++mf)
        #pragma unroll
        for (int nf = 0; nf < 4; ++nf)
          oacc[mf][nf] = __builtin_amdgcn_mfma_f32_16x16x32_bf16(
              pa[mf], vb[nf], oacc[mf][nf], 0, 0, 0);
    }
  }

  __syncthreads();
  float rinv[2][4];
  #pragma unroll
  for (int mf = 0; mf < 2; ++mf)
    #pragma unroll
    for (int r2 = 0; r2 < 4; ++r2) rinv[mf][r2] = 1.f / l_[mf][r2];
  #pragma unroll
  for (int mf = 0; mf < 2; ++mf)
    #pragma unroll
    for (int nf = 0; nf < 4; ++nf)
      #pragma unroll
      for (int r2 = 0; r2 < 4; ++r2)
        Obuf[(nf * 16 + ll) * 130 + w * 32 + mf * 16 + lh * 4 + r2] =
            oacc[mf][nf][r2] * rinv[mf][r2];
  __syncthreads();
  #pragma unroll 4
  for (int j = 0; j < 32; ++j) {
    int idx = t + 256 * j;
    int e = idx >> 7, ql = idx & 127;
    int s = qbase + ql;
    int c = cbase + (e & 15), fr = e >> 4;
    int y = s / 28, x = s - (s / 28) * 28;
    out[(((size_t)(b * C_N + c)) * 4 + fr) * HW_N + s] =
        Obuf[e * 130 + ql] + rel_t2[c * 4 + fr] + rel_h2[c * 28 + y]
        + rel_w2[c * 28 + x];
  }
}

extern "C" void kernel_launch(void* const* d_in, const int* in_sizes, int n_in,
                              void* d_out, int out_size, void* d_ws, size_t ws_size,
                              hipStream_t stream) {
  const float* x     = (const float*)d_in[0];
  const float* Wq    = (const float*)d_in[1];
  const float* Wk    = (const float*)d_in[2];
  const float* Wv1   = (const float*)d_in[3];
  const float* Wv2   = (const float*)d_in[4];
  const float* relh  = (const float*)d_in[5];
  const float* relw  = (const float*)d_in[6];
  const float* relt  = (const float*)d_in[7];
  const float* relh2 = (const float*)d_in[8];
  const float* relw2 = (const float*)d_in[9];
  const float* relt2 = (const float*)d_in[10];
  float* out = (float*)d_out;
  char* ws = (char*)d_ws;

  const size_t NE = (size_t)NTOT * C_N;
  u16* xt   = (u16*)(ws);            // xt, then v0 (planar) after xt is dead
  u16* q0   = (u16*)(ws + NE * 2);   // q channels-last
  u16* t0   = (u16*)(ws + NE * 4);   // v1 = conv311(x, Wv1) channels-last
  u16* k0   = (u16*)(ws + NE * 6);   // k channels-last
  u16* wqb  = (u16*)(ws + NE * 8);
  u16* wkb  = (u16*)(ws + NE * 8 + 4718592);
  u16* wv1b = (u16*)(ws + NE * 8 + 4718592 + 1572864);
  u16* wv2b = (u16*)(ws + NE * 8 + 4718592 + 2 * 1572864);
  u16* zbuf = (u16*)(ws + NE * 8 + 2 * 4718592 + 2 * 1572864);

  zerok<<<dim3(4), dim3(256), 0, stream>>>((float*)zbuf);
  pack_w<9><<<dim3(9216), dim3(256), 0, stream>>>(Wq,  wqb,  9 * C_N * C_N);
  pack_w<3><<<dim3(3072), dim3(256), 0, stream>>>(Wk,  wkb,  3 * C_N * C_N);
  pack_w<3><<<dim3(3072), dim3(256), 0, stream>>>(Wv1, wv1b, 3 * C_N * C_N);
  pack_w<9><<<dim3(9216), dim3(256), 0, stream>>>(Wv2, wv2b, 9 * C_N * C_N);
  cast_transpose<<<dim3(16, 13, 8), dim3(256), 0, stream>>>(x, xt);

  dim3 cgrid(98, 4), blk(256);
  // k = conv311(x, Wk), v1 = conv311(x, Wv1)  (legal fusion: same input x)
  conv311_dual<<<cgrid, blk, 0, stream>>>(xt, wkb, wv1b, k0, t0, zbuf);
  // q = conv133(x, Wq) channels-last
  conv_mfma32<9, 1><<<cgrid, blk, 0, stream>>>(xt, wqb, q0, zbuf);
  // v = conv133(v1, Wv2) planar, into the now-dead xt slab  (reference order!)
  conv_mfma32<9, 2><<<cgrid, blk, 0, stream>>>(t0, wv2b, xt, zbuf);

  attn_mfma<<<dim3(896), blk, 0, stream>>>(
      q0, k0, xt, relh, relw, relt, relh2, relw2, relt2, out);
}

// Round 8
// 429.105 us; speedup vs baseline: 1.4352x; 1.0375x over previous
//
#include <hip/hip_runtime.h>
#include <hip/hip_bf16.h>

#define B_N 4
#define C_N 512
#define F_N 4
#define HW_N 784
#define PL (F_N * HW_N)        // 3136 per (b,c) plane
#define NTOT 12544             // 16 * 784 columns

typedef unsigned short u16;
typedef __attribute__((ext_vector_type(8))) short bf16x8;
typedef __attribute__((ext_vector_type(4))) float f32x4;
typedef __attribute__((ext_vector_type(16))) float f32x16;

__device__ __forceinline__ u16 f2b(float x) {
  unsigned u = __float_as_uint(x);
  unsigned r = ((u >> 16) & 1u) + 0x7fffu;
  return (u16)((u + r) >> 16);
}

typedef const __attribute__((address_space(1))) unsigned int* gas_ptr;
typedef __attribute__((address_space(3))) unsigned int* las_ptr;
__device__ __forceinline__ void gl_lds16(const void* g, void* l) {
  __builtin_amdgcn_global_load_lds((gas_ptr)(unsigned long long)(g),
                                   (las_ptr)(unsigned)(unsigned long long)(l),
                                   16, 0, 0);
}

// ---------------- zero small pad buffer ----------------
__global__ void zerok(float* z) { z[blockIdx.x * 256 + threadIdx.x] = 0.f; }

// ---------------- fused weight pack: all 4 weights in one launch ----------
__global__ __launch_bounds__(256) void pack_all(
    const float* __restrict__ Wq, const float* __restrict__ Wk,
    const float* __restrict__ Wv1, const float* __restrict__ Wv2,
    u16* __restrict__ wqb, u16* __restrict__ wkb,
    u16* __restrict__ wv1b, u16* __restrict__ wv2b) {
  int idx = blockIdx.x * 256 + threadIdx.x;
  const int CC = C_N * C_N;            // 262144 = 2^18
  const int S9 = 9 * CC, S3 = 3 * CC;
  const float* w; u16* o; int taps; int r;
  if (idx < S9)               { w = Wq;  o = wqb;  taps = 9; r = idx; }
  else if (idx < S9 + S3)     { w = Wk;  o = wkb;  taps = 3; r = idx - S9; }
  else if (idx < S9 + 2 * S3) { w = Wv1; o = wv1b; taps = 3; r = idx - S9 - S3; }
  else                        { w = Wv2; o = wv2b; taps = 9; r = idx - S9 - 2 * S3; }
  int tap = r >> 18, rem = r & (CC - 1);
  o[r] = f2b(w[(size_t)rem * taps + tap]);
}

// ---------------- cast+transpose: x f32 NCDHW -> xt bf16 [bf*784+s][512] ----
__global__ __launch_bounds__(256) void cast_transpose(const float* __restrict__ x,
                                                      u16* __restrict__ xt) {
  const int bf = blockIdx.x, st = blockIdx.y, ct = blockIdx.z;
  const int b = bf >> 2, f = bf & 3;
  const int s0 = st * 64, c0 = ct * 64;
  const int tx = threadIdx.x & 63, ty = threadIdx.x >> 6;
  __shared__ float tile[64][65];
  const float* src = x + ((size_t)(b * C_N + c0)) * PL + (size_t)f * HW_N + s0;
  #pragma unroll
  for (int i = 0; i < 16; ++i) {
    int c = ty + i * 4;
    float v = 0.f;
    if (s0 + tx < HW_N) v = src[(size_t)c * PL + tx];
    tile[c][tx] = v;
  }
  __syncthreads();
  #pragma unroll
  for (int i = 0; i < 16; ++i) {
    int srow = ty + i * 4;
    int ss = s0 + srow;
    if (ss < HW_N) xt[((size_t)bf * HW_N + ss) * C_N + c0 + tx] = f2b(tile[tx][srow]);
  }
}

// ---------------- fused conv133 (q + v), double-buffered, 32x32x16 ---------
// z=0: q = conv133(xt, wq) -> channels-last.  z=1: v = conv133(t0, wv) -> planar.
__global__ __launch_bounds__(256) void conv133_qv(
    const u16* __restrict__ xt, const u16* __restrict__ t0,
    const u16* __restrict__ wq, const u16* __restrict__ wv,
    u16* __restrict__ q0, u16* __restrict__ v0, const u16* __restrict__ zbuf)
{
  const int which = blockIdx.z;
  const u16* xin = which ? t0 : xt;
  const u16* wb  = which ? wv : wq;
  u16* outp      = which ? v0 : q0;

  const int nt = blockIdx.x;       // 98
  const int cot = blockIdx.y;      // 4
  const int cobase = cot << 7;
  const int t = threadIdx.x;
  const int wv_ = t >> 6, l = t & 63;
  const int wm = wv_ >> 1, wn = wv_ & 1;
  const int l31 = l & 31, lk2 = l >> 5;

  __shared__ u16 Xs[2][128 * 64];  // 32 KB
  __shared__ u16 Ws[2][128 * 64];  // 32 KB

  const int crow = l >> 3;
  const int chunk = (l & 7) ^ (crow & 7);

  int gcol[4], sy[4], sx[4];
  const u16* xbase[4];
  const u16* wbase[4];
  #pragma unroll
  for (int i = 0; i < 4; ++i) {
    gcol[i] = nt * 128 + wv_ * 32 + i * 8 + crow;
    int s = gcol[i] % HW_N;
    sy[i] = s / 28; sx[i] = s - (s / 28) * 28;
    xbase[i] = xin + (size_t)gcol[i] * C_N + chunk * 8;
    int co = cobase + wv_ * 32 + i * 8 + crow;
    wbase[i] = wb + (size_t)co * C_N + chunk * 8;
  }
  const u16* zsrc = zbuf + chunk * 8;

  f32x16 acc[2][2];
  #pragma unroll
  for (int fm = 0; fm < 2; ++fm)
    #pragma unroll
    for (int fn = 0; fn < 2; ++fn)
      #pragma unroll
      for (int e = 0; e < 16; ++e) acc[fm][fn][e] = 0.f;

  const int NIT = 72;

  auto STAGE = [&](int idx, int sel) {
    int tap = idx >> 3, kb = idx & 7;
    int dy = (tap * 11) >> 5, dx = tap - dy * 3;
    int off = (dy - 1) * 28 + (dx - 1);
    #pragma unroll
    for (int i = 0; i < 4; ++i) {
      int yy = sy[i] + dy - 1, xx = sx[i] + dx - 1;
      bool valid = ((unsigned)yy < 28u) && ((unsigned)xx < 28u);
      const u16* sx_ = valid ? (xbase[i] + off * (int)C_N + kb * 64) : zsrc;
      const u16* sw_ = wbase[i] + tap * (C_N * C_N) + kb * 64;
      gl_lds16(sx_, (void*)(&Xs[sel][0] + (wv_ * 4 + i) * 512));
      gl_lds16(sw_, (void*)(&Ws[sel][0] + (wv_ * 4 + i) * 512));
    }
  };

  auto COMPUTE = [&](int sel) {
    #pragma unroll
    for (int kc = 0; kc < 4; ++kc) {
      const int slot = (kc * 2 + lk2) ^ (l31 & 7);
      bf16x8 af[2], bx[2];
      #pragma unroll
      for (int fm = 0; fm < 2; ++fm)
        af[fm] = *(const bf16x8*)&Ws[sel][(wm * 64 + fm * 32 + l31) * 64 + slot * 8];
      #pragma unroll
      for (int fn = 0; fn < 2; ++fn)
        bx[fn] = *(const bf16x8*)&Xs[sel][(wn * 64 + fn * 32 + l31) * 64 + slot * 8];
      #pragma unroll
      for (int fm = 0; fm < 2; ++fm)
        #pragma unroll
        for (int fn = 0; fn < 2; ++fn)
          acc[fm][fn] = __builtin_amdgcn_mfma_f32_32x32x16_bf16(
              af[fm], bx[fn], acc[fm][fn], 0, 0, 0);
    }
  };

  STAGE(0, 0);
  __syncthreads();
  for (int base = 0; base < NIT; base += 2) {
    if (base + 1 < NIT) STAGE(base + 1, 1);
    COMPUTE(0);
    __syncthreads();
    if (base + 2 < NIT) STAGE(base + 2, 0);
    COMPUTE(1);
    __syncthreads();
  }

  // C layout (32x32): col=lane&31 (n), row=(reg&3)+8*(reg>>2)+4*(lane>>5) (co)
  #pragma unroll
  for (int fn = 0; fn < 2; ++fn) {
    int n = nt * 128 + wn * 64 + fn * 32 + l31;
    if (which == 0) {
      #pragma unroll
      for (int fm = 0; fm < 2; ++fm) {
        int cob = cobase + wm * 64 + fm * 32 + lk2 * 4;
        #pragma unroll
        for (int rg = 0; rg < 4; ++rg) {
          ushort4 pk;
          pk.x = f2b(acc[fm][fn][rg * 4 + 0]);
          pk.y = f2b(acc[fm][fn][rg * 4 + 1]);
          pk.z = f2b(acc[fm][fn][rg * 4 + 2]);
          pk.w = f2b(acc[fm][fn][rg * 4 + 3]);
          *(ushort4*)&outp[(size_t)n * C_N + cob + rg * 8] = pk;
        }
      }
    } else {
      int bf = n / HW_N, s = n - (n / HW_N) * HW_N;
      int b = bf >> 2, f = bf & 3;
      #pragma unroll
      for (int fm = 0; fm < 2; ++fm) {
        int cob = cobase + wm * 64 + fm * 32 + lk2 * 4;
        #pragma unroll
        for (int rg = 0; rg < 4; ++rg)
          #pragma unroll
          for (int j = 0; j < 4; ++j) {
            int co = cob + rg * 8 + j;
            outp[((size_t)(b * C_N + co)) * PL + (size_t)f * HW_N + s] =
                f2b(acc[fm][fn][rg * 4 + j]);
          }
      }
    }
  }
}

// ---------------- dual-output conv311: k and v1 share X staging ------------
__global__ __launch_bounds__(256, 2) void conv311_dual(
    const u16* __restrict__ xin, const u16* __restrict__ wa,
    const u16* __restrict__ wc, u16* __restrict__ outa,
    u16* __restrict__ outc, const u16* __restrict__ zbuf)
{
  const int nt = blockIdx.x;       // 98
  const int cot = blockIdx.y;      // 4
  const int cobase = cot << 7;
  const int t = threadIdx.x;
  const int wv = t >> 6, l = t & 63;
  const int wm = wv >> 1, wn = wv & 1;
  const int l31 = l & 31, lk2 = l >> 5;

  __shared__ u16 Xs[128 * 64];
  __shared__ u16 Was[128 * 64];
  __shared__ u16 Wcs[128 * 64];

  const int crow = l >> 3;
  const int chunk = (l & 7) ^ (crow & 7);

  int gcol[4], sf[4];
  #pragma unroll
  for (int i = 0; i < 4; ++i) {
    gcol[i] = nt * 128 + wv * 32 + i * 8 + crow;
    sf[i] = (gcol[i] / HW_N) & 3;
  }

  f32x16 acca[2][2], accc[2][2];
  #pragma unroll
  for (int fm = 0; fm < 2; ++fm)
    #pragma unroll
    for (int fn = 0; fn < 2; ++fn)
      #pragma unroll
      for (int e = 0; e < 16; ++e) { acca[fm][fn][e] = 0.f; accc[fm][fn][e] = 0.f; }

  for (int tap = 0; tap < 3; ++tap) {
    const u16* xp[4];
    const u16* wpa[4];
    const u16* wpc[4];
    int off = (tap - 1) * HW_N;
    #pragma unroll
    for (int i = 0; i < 4; ++i) {
      int ff = sf[i] + tap - 1;
      bool valid = ((unsigned)ff < 4u);
      xp[i] = valid ? (xin + (size_t)(gcol[i] + off) * C_N + chunk * 8)
                    : (zbuf + chunk * 8);
      int co = cobase + wv * 32 + i * 8 + crow;
      wpa[i] = wa + ((size_t)tap * C_N + co) * C_N + chunk * 8;
      wpc[i] = wc + ((size_t)tap * C_N + co) * C_N + chunk * 8;
    }
    for (int kb = 0; kb < 8; ++kb) {
      __syncthreads();
      #pragma unroll
      for (int i = 0; i < 4; ++i) {
        gl_lds16(xp[i],  (void*)(Xs  + (wv * 4 + i) * 512));
        gl_lds16(wpa[i], (void*)(Was + (wv * 4 + i) * 512));
        gl_lds16(wpc[i], (void*)(Wcs + (wv * 4 + i) * 512));
        xp[i] += 64; wpa[i] += 64; wpc[i] += 64;
      }
      __syncthreads();
      #pragma unroll
      for (int kc = 0; kc < 4; ++kc) {
        const int slot = (kc * 2 + lk2) ^ (l31 & 7);
        bf16x8 afa[2], afc[2], bx[2];
        #pragma unroll
        for (int fm = 0; fm < 2; ++fm) {
          afa[fm] = *(const bf16x8*)&Was[(wm * 64 + fm * 32 + l31) * 64 + slot * 8];
          afc[fm] = *(const bf16x8*)&Wcs[(wm * 64 + fm * 32 + l31) * 64 + slot * 8];
        }
        #pragma unroll
        for (int fn = 0; fn < 2; ++fn)
          bx[fn] = *(const bf16x8*)&Xs[(wn * 64 + fn * 32 + l31) * 64 + slot * 8];
        #pragma unroll
        for (int fm = 0; fm < 2; ++fm)
          #pragma unroll
          for (int fn = 0; fn < 2; ++fn) {
            acca[fm][fn] = __builtin_amdgcn_mfma_f32_32x32x16_bf16(
                afa[fm], bx[fn], acca[fm][fn], 0, 0, 0);
            accc[fm][fn] = __builtin_amdgcn_mfma_f32_32x32x16_bf16(
                afc[fm], bx[fn], accc[fm][fn], 0, 0, 0);
          }
      }
    }
  }

  #pragma unroll
  for (int fn = 0; fn < 2; ++fn) {
    int n = nt * 128 + wn * 64 + fn * 32 + l31;
    #pragma unroll
    for (int fm = 0; fm < 2; ++fm) {
      int cob = cobase + wm * 64 + fm * 32 + lk2 * 4;
      #pragma unroll
      for (int rg = 0; rg < 4; ++rg) {
        ushort4 pa, pc;
        pa.x = f2b(acca[fm][fn][rg * 4 + 0]); pa.y = f2b(acca[fm][fn][rg * 4 + 1]);
        pa.z = f2b(acca[fm][fn][rg * 4 + 2]); pa.w = f2b(acca[fm][fn][rg * 4 + 3]);
        pc.x = f2b(accc[fm][fn][rg * 4 + 0]); pc.y = f2b(accc[fm][fn][rg * 4 + 1]);
        pc.z = f2b(accc[fm][fn][rg * 4 + 2]); pc.w = f2b(accc[fm][fn][rg * 4 + 3]);
        *(ushort4*)&outa[(size_t)n * C_N + cob + rg * 8] = pa;
        *(ushort4*)&outc[(size_t)n * C_N + cob + rg * 8] = pc;
      }
    }
  }
}

// ---------------- MFMA fused attention (fixed-shift softmax, K/V dbuf) -----
__global__ __launch_bounds__(256, 2) void attn_mfma(
    const u16* __restrict__ q0, const u16* __restrict__ k0,
    const u16* __restrict__ v0,
    const float* __restrict__ rel_h, const float* __restrict__ rel_w,
    const float* __restrict__ rel_t, const float* __restrict__ rel_h2,
    const float* __restrict__ rel_w2, const float* __restrict__ rel_t2,
    float* __restrict__ out)
{
  // XCD-affine decode: all 7 q-tiles of a group land on one XCD (bid%8 const)
  const int bid = blockIdx.x;            // 896
  const int xcd = bid & 7, r = bid >> 3;
  const int gi = r / 7, qt = r - gi * 7;
  const int g = gi * 8 + xcd;
  const int b = g >> 5, gg = g & 31;
  const int cbase = gg << 4, h = gg >> 2, fgrp = gg & 3;
  const int qbase = min(qt * 128, 656);
  const int t = threadIdx.x;
  const int w = t >> 6, lane = t & 63, ll = lane & 15, lh = lane >> 4;

  __shared__ __align__(16) u16 smem[32768];        // 64 KB
  // Bp[2][64][128] @0, Vt[2][64][64] @16384, Pm[128][64] @24576
  u16* Pm = smem + 24576;
  float* Obuf = (float*)smem;                      // [64 e][130 q] (epilogue)

  const size_t slab = ((size_t)b * C_N + cbase) * PL;

  // A-operand in registers: Qt (global) + P (rel sums), k-tile invariant
  bf16x8 afr[2][4];
  #pragma unroll
  for (int mf = 0; mf < 2; ++mf) {
    const int q = qbase + w * 32 + mf * 16 + ll;
    const int y = q / 28, x = q - (q / 28) * 28;
    #pragma unroll
    for (int kk = 0; kk < 2; ++kk) {
      int c = kk * 4 + lh;
      afr[mf][kk] = *(const bf16x8*)&q0[((size_t)((b * 4 + (c >> 1)) * HW_N + q)) * C_N
                                        + cbase + (c & 1) * 8];
    }
    #pragma unroll
    for (int kk = 0; kk < 2; ++kk) {
      int ebase = kk * 32 + lh * 8;
      bf16x8 pv;
      #pragma unroll
      for (int j = 0; j < 8; ++j) {
        int e = ebase + j;
        int di = (e & 15) * 4 + (e >> 4);
        int idx = h * 64 + di;
        pv[j] = (short)f2b(rel_h[idx * 28 + y] + rel_w[idx * 28 + x]
                           + rel_t[idx * 4 + fgrp]);
      }
      afr[mf][2 + kk] = pv;
    }
  }

  f32x4 oacc[2][4];
  float l_[2][4];
  #pragma unroll
  for (int mf = 0; mf < 2; ++mf)
    #pragma unroll
    for (int nf = 0; nf < 4; ++nf) oacc[mf][nf] = (f32x4){0.f, 0.f, 0.f, 0.f};
  #pragma unroll
  for (int mf = 0; mf < 2; ++mf)
    #pragma unroll
    for (int r2 = 0; r2 < 4; ++r2) l_[mf][r2] = 0.f;

  auto STAGE = [&](int kt, int sel) {
    const int kbase = kt * 64;
    #pragma unroll
    for (int i = 0; i < 4; ++i) {
      int krow = w * 16 + i * 4 + lh;
      int c = (ll & 8) | ((ll ^ krow) & 7);
      int cc = c & 7;
      const u16* bsrc = (c < 8) ? k0 : q0;
      const u16* src = bsrc + ((size_t)((b * 4 + (cc >> 1)) * HW_N + kbase + krow)) * C_N
                       + cbase + (cc & 1) * 8;
      gl_lds16(src, (void*)(smem + sel * 8192 + (w * 16 + i * 4) * 128));
    }
    #pragma unroll
    for (int i = 0; i < 2; ++i) {
      int e = w * 16 + i * 8 + (lane >> 3);
      int ch = (lane & 7) ^ (e & 7);
      int di = (e & 15) * 4 + (e >> 4);
      const u16* src = v0 + slab + (size_t)di * HW_N + kbase + ch * 8;
      gl_lds16(src, (void*)(smem + 16384 + sel * 4096 + (w * 16 + i * 8) * 64));
    }
  };

  // p = exp(S/8 - 8) = 2^(S*0.1803369 - 11.5415603); shift-invariant softmax,
  // statistically safe: S ~ N(0, ~2.8), overflow needs S > ~770.
  const float C1 = 0.18033688f;
  const float C2 = -11.5415603f;

  STAGE(0, 0);
  __syncthreads();

  for (int kt = 0; kt < 13; ++kt) {
    const int cur = kt & 1;
    if (kt < 12) STAGE(kt + 1, cur ^ 1);
    const int kbase = kt * 64;
    const u16* BpC = smem + cur * 8192;
    const u16* VtC = smem + 16384 + cur * 4096;

    f32x4 sacc[2][4];
    #pragma unroll
    for (int mf = 0; mf < 2; ++mf)
      #pragma unroll
      for (int nf = 0; nf < 4; ++nf) sacc[mf][nf] = (f32x4){0.f, 0.f, 0.f, 0.f};
    #pragma unroll
    for (int kk = 0; kk < 4; ++kk) {
      bf16x8 bx[4];
      #pragma unroll
      for (int nf = 0; nf < 4; ++nf) {
        int slot = (kk * 4 + lh) ^ (ll & 7);
        bx[nf] = *(const bf16x8*)&BpC[(nf * 16 + ll) * 128 + slot * 8];
      }
      #pragma unroll
      for (int mf = 0; mf < 2; ++mf)
        #pragma unroll
        for (int nf = 0; nf < 4; ++nf)
          sacc[mf][nf] = __builtin_amdgcn_mfma_f32_16x16x32_bf16(
              afr[mf][kk], bx[nf], sacc[mf][nf], 0, 0, 0);
    }

    bool kval[4];
    #pragma unroll
    for (int nf = 0; nf < 4; ++nf) kval[nf] = (kbase + nf * 16 + ll) < HW_N;
    #pragma unroll
    for (int mf = 0; mf < 2; ++mf) {
      const int qlb = w * 32 + mf * 16;
      #pragma unroll
      for (int r2 = 0; r2 < 4; ++r2) {
        float p0 = __builtin_amdgcn_exp2f(fmaf(sacc[mf][0][r2], C1, C2));
        float p1 = __builtin_amdgcn_exp2f(fmaf(sacc[mf][1][r2], C1, C2));
        float p2 = __builtin_amdgcn_exp2f(fmaf(sacc[mf][2][r2], C1, C2));
        float p3 = __builtin_amdgcn_exp2f(fmaf(sacc[mf][3][r2], C1, C2));
        if (!kval[0]) p0 = 0.f;
        if (!kval[1]) p1 = 0.f;
        if (!kval[2]) p2 = 0.f;
        if (!kval[3]) p3 = 0.f;
        float psum = (p0 + p1) + (p2 + p3);
        #pragma unroll
        for (int off = 8; off >= 1; off >>= 1)
          psum += __shfl_xor(psum, off);
        l_[mf][r2] += psum;
        const int ql = qlb + lh * 4 + r2;
        const int swz = (ql & 7);
        Pm[ql * 64 + ((((ll >> 3))     ^ swz) * 8) + (ll & 7)] = f2b(p0);
        Pm[ql * 64 + (((2 + (ll >> 3)) ^ swz) * 8) + (ll & 7)] = f2b(p1);
        Pm[ql * 64 + (((4 + (ll >> 3)) ^ swz) * 8) + (ll & 7)] = f2b(p2);
        Pm[ql * 64 + (((6 + (ll >> 3)) ^ swz) * 8) + (ll & 7)] = f2b(p3);
      }
    }
    // Pm rows written+read by the SAME wave -> no barrier needed.

    #pragma unroll
    for (int ks = 0; ks < 2; ++ks) {
      bf16x8 pa[2], vb[4];
      #pragma unroll
      for (int mf = 0; mf < 2; ++mf) {
        int ql = w * 32 + mf * 16 + ll;
        int slot = (ks * 4 + lh) ^ (ql & 7);
        pa[mf] = *(const bf16x8*)&Pm[ql * 64 + slot * 8];
      }
      #pragma unroll
      for (int nf = 0; nf < 4; ++nf) {
        int e = nf * 16 + ll;
        int slot = (ks * 4 + lh) ^ (e & 7);
        vb[nf] = *(const bf16x8*)&VtC[e * 64 + slot * 8];
      }
      #pragma unroll
      for (int mf = 0; mf < 2; ++mf)
        #pragma unroll
        for (int nf = 0; nf < 4; ++nf)
          oacc[mf][nf] = __builtin_amdgcn_mfma_f32_16x16x32_bf16(
              pa[mf], vb[nf], oacc[mf][nf], 0, 0, 0);
    }
    __syncthreads();   // drains stage(kt+1); buf (kt-1)%2 safe to rewrite
  }

  float rinv[2][4];
  #pragma unroll
  for (int mf = 0; mf < 2; ++mf)
    #pragma unroll
    for (int r2 = 0; r2 < 4; ++r2) rinv[mf][r2] = 1.f / l_[mf][r2];
  #pragma unroll
  for (int mf = 0; mf < 2; ++mf)
    #pragma unroll
    for (int nf = 0; nf < 4; ++nf)
      #pragma unroll
      for (int r2 = 0; r2 < 4; ++r2)
        Obuf[(nf * 16 + ll) * 130 + w * 32 + mf * 16 + lh * 4 + r2] =
            oacc[mf][nf][r2] * rinv[mf][r2];
  __syncthreads();
  #pragma unroll 4
  for (int j = 0; j < 32; ++j) {
    int idx = t + 256 * j;
    int e = idx >> 7, ql = idx & 127;
    int s = qbase + ql;
    int c = cbase + (e & 15), fr = e >> 4;
    int y = s / 28, x = s - (s / 28) * 28;
    out[(((size_t)(b * C_N + c)) * 4 + fr) * HW_N + s] =
        Obuf[e * 130 + ql] + rel_t2[c * 4 + fr] + rel_h2[c * 28 + y]
        + rel_w2[c * 28 + x];
  }
}

extern "C" void kernel_launch(void* const* d_in, const int* in_sizes, int n_in,
                              void* d_out, int out_size, void* d_ws, size_t ws_size,
                              hipStream_t stream) {
  const float* x     = (const float*)d_in[0];
  const float* Wq    = (const float*)d_in[1];
  const float* Wk    = (const float*)d_in[2];
  const float* Wv1   = (const float*)d_in[3];
  const float* Wv2   = (const float*)d_in[4];
  const float* relh  = (const float*)d_in[5];
  const float* relw  = (const float*)d_in[6];
  const float* relt  = (const float*)d_in[7];
  const float* relh2 = (const float*)d_in[8];
  const float* relw2 = (const float*)d_in[9];
  const float* relt2 = (const float*)d_in[10];
  float* out = (float*)d_out;
  char* ws = (char*)d_ws;

  const size_t NE = (size_t)NTOT * C_N;    // 6,422,528 elements
  u16* xt   = (u16*)(ws);                  // x channels-last
  u16* q0   = (u16*)(ws + NE * 2);         // q channels-last
  u16* t0   = (u16*)(ws + NE * 4);         // v1 = conv311(x, Wv1) channels-last
  u16* k0   = (u16*)(ws + NE * 6);         // k channels-last
  u16* v0   = (u16*)(ws + NE * 8);         // v planar
  u16* wqb  = (u16*)(ws + NE * 10);
  u16* wkb  = (u16*)(ws + NE * 10 + 4718592);
  u16* wv1b = (u16*)(ws + NE * 10 + 4718592 + 1572864);
  u16* wv2b = (u16*)(ws + NE * 10 + 4718592 + 2 * 1572864);
  u16* zbuf = (u16*)(ws + NE * 10 + 2 * 4718592 + 2 * 1572864);  // 4 KB zeros

  zerok<<<dim3(4), dim3(256), 0, stream>>>((float*)zbuf);
  pack_all<<<dim3(24576), dim3(256), 0, stream>>>(
      Wq, Wk, Wv1, Wv2, wqb, wkb, wv1b, wv2b);
  cast_transpose<<<dim3(16, 13, 8), dim3(256), 0, stream>>>(x, xt);

  dim3 blk(256);
  // k = conv311(x, Wk), v1 = conv311(x, Wv1)
  conv311_dual<<<dim3(98, 4), blk, 0, stream>>>(xt, wkb, wv1b, k0, t0, zbuf);
  // q = conv133(x, Wq) [z=0], v = conv133(v1, Wv2) [z=1] — fused launch
  conv133_qv<<<dim3(98, 4, 2), blk, 0, stream>>>(xt, t0, wqb, wv2b, q0, v0, zbuf);

  attn_mfma<<<dim3(896), blk, 0, stream>>>(
      q0, k0, v0, relh, relw, relt, relh2, relw2, relt2, out);
}

// Round 9
// 409.509 us; speedup vs baseline: 1.5038x; 1.0479x over previous
//
#include <hip/hip_runtime.h>
#include <hip/hip_bf16.h>

#define B_N 4
#define C_N 512
#define F_N 4
#define HW_N 784
#define PL (F_N * HW_N)        // 3136 per (b,c) plane
#define NTOT 12544             // 16 * 784 columns

typedef unsigned short u16;
typedef __attribute__((ext_vector_type(8))) short bf16x8;
typedef __attribute__((ext_vector_type(4))) float f32x4;
typedef __attribute__((ext_vector_type(16))) float f32x16;

__device__ __forceinline__ u16 f2b(float x) {
  unsigned u = __float_as_uint(x);
  unsigned r = ((u >> 16) & 1u) + 0x7fffu;
  return (u16)((u + r) >> 16);
}

typedef const __attribute__((address_space(1))) unsigned int* gas_ptr;
typedef __attribute__((address_space(3))) unsigned int* las_ptr;
__device__ __forceinline__ void gl_lds16(const void* g, void* l) {
  __builtin_amdgcn_global_load_lds((gas_ptr)(unsigned long long)(g),
                                   (las_ptr)(unsigned)(unsigned long long)(l),
                                   16, 0, 0);
}

// ---------------- zero small pad buffer ----------------
__global__ void zerok(float* z) { z[blockIdx.x * 256 + threadIdx.x] = 0.f; }

// ---------------- fused weight pack: all 4 weights in one launch ----------
__global__ __launch_bounds__(256) void pack_all(
    const float* __restrict__ Wq, const float* __restrict__ Wk,
    const float* __restrict__ Wv1, const float* __restrict__ Wv2,
    u16* __restrict__ wqb, u16* __restrict__ wkb,
    u16* __restrict__ wv1b, u16* __restrict__ wv2b) {
  int idx = blockIdx.x * 256 + threadIdx.x;
  const int CC = C_N * C_N;            // 262144 = 2^18
  const int S9 = 9 * CC, S3 = 3 * CC;
  const float* w; u16* o; int taps; int r;
  if (idx < S9)               { w = Wq;  o = wqb;  taps = 9; r = idx; }
  else if (idx < S9 + S3)     { w = Wk;  o = wkb;  taps = 3; r = idx - S9; }
  else if (idx < S9 + 2 * S3) { w = Wv1; o = wv1b; taps = 3; r = idx - S9 - S3; }
  else                        { w = Wv2; o = wv2b; taps = 9; r = idx - S9 - 2 * S3; }
  int tap = r >> 18, rem = r & (CC - 1);
  o[r] = f2b(w[(size_t)rem * taps + tap]);
}

// ---------------- cast+transpose: x f32 NCDHW -> xt bf16 [bf*784+s][512] ----
__global__ __launch_bounds__(256) void cast_transpose(const float* __restrict__ x,
                                                      u16* __restrict__ xt) {
  const int bf = blockIdx.x, st = blockIdx.y, ct = blockIdx.z;
  const int b = bf >> 2, f = bf & 3;
  const int s0 = st * 64, c0 = ct * 64;
  const int tx = threadIdx.x & 63, ty = threadIdx.x >> 6;
  __shared__ float tile[64][65];
  const float* src = x + ((size_t)(b * C_N + c0)) * PL + (size_t)f * HW_N + s0;
  #pragma unroll
  for (int i = 0; i < 16; ++i) {
    int c = ty + i * 4;
    float v = 0.f;
    if (s0 + tx < HW_N) v = src[(size_t)c * PL + tx];
    tile[c][tx] = v;
  }
  __syncthreads();
  #pragma unroll
  for (int i = 0; i < 16; ++i) {
    int srow = ty + i * 4;
    int ss = s0 + srow;
    if (ss < HW_N) xt[((size_t)bf * HW_N + ss) * C_N + c0 + tx] = f2b(tile[tx][srow]);
  }
}

// ---------------- fused conv133 (q + v), double-buffered, 32x32x16 ---------
// XCD-affine: 1D grid 784; combo=bid&7 -> (cot,which), nt=bid>>3. All blocks
// on one XCD share the same weight panel (L2-resident) and input (L3).
__global__ __launch_bounds__(256) void conv133_qv(
    const u16* __restrict__ xt, const u16* __restrict__ t0,
    const u16* __restrict__ wq, const u16* __restrict__ wv,
    u16* __restrict__ q0, u16* __restrict__ v0, const u16* __restrict__ zbuf)
{
  const int bid = blockIdx.x;      // 784
  const int combo = bid & 7;
  const int nt = bid >> 3;         // 0..97
  const int cot = combo >> 1;
  const int which = combo & 1;
  const u16* xin = which ? t0 : xt;
  const u16* wb  = which ? wv : wq;
  u16* outp      = which ? v0 : q0;

  const int cobase = cot << 7;
  const int t = threadIdx.x;
  const int wv_ = t >> 6, l = t & 63;
  const int wm = wv_ >> 1, wn = wv_ & 1;
  const int l31 = l & 31, lk2 = l >> 5;

  __shared__ u16 Xs[2][128 * 64];  // 32 KB
  __shared__ u16 Ws[2][128 * 64];  // 32 KB

  const int crow = l >> 3;
  const int chunk = (l & 7) ^ (crow & 7);

  int gcol[4], sy[4], sx[4];
  const u16* xbase[4];
  const u16* wbase[4];
  #pragma unroll
  for (int i = 0; i < 4; ++i) {
    gcol[i] = nt * 128 + wv_ * 32 + i * 8 + crow;
    int s = gcol[i] % HW_N;
    sy[i] = s / 28; sx[i] = s - (s / 28) * 28;
    xbase[i] = xin + (size_t)gcol[i] * C_N + chunk * 8;
    int co = cobase + wv_ * 32 + i * 8 + crow;
    wbase[i] = wb + (size_t)co * C_N + chunk * 8;
  }
  const u16* zsrc = zbuf + chunk * 8;

  f32x16 acc[2][2];
  #pragma unroll
  for (int fm = 0; fm < 2; ++fm)
    #pragma unroll
    for (int fn = 0; fn < 2; ++fn)
      #pragma unroll
      for (int e = 0; e < 16; ++e) acc[fm][fn][e] = 0.f;

  const int NIT = 72;

  auto STAGE = [&](int idx, int sel) {
    int tap = idx >> 3, kb = idx & 7;
    int dy = (tap * 11) >> 5, dx = tap - dy * 3;
    int off = (dy - 1) * 28 + (dx - 1);
    #pragma unroll
    for (int i = 0; i < 4; ++i) {
      int yy = sy[i] + dy - 1, xx = sx[i] + dx - 1;
      bool valid = ((unsigned)yy < 28u) && ((unsigned)xx < 28u);
      const u16* sx_ = valid ? (xbase[i] + off * (int)C_N + kb * 64) : zsrc;
      const u16* sw_ = wbase[i] + tap * (C_N * C_N) + kb * 64;
      gl_lds16(sx_, (void*)(&Xs[sel][0] + (wv_ * 4 + i) * 512));
      gl_lds16(sw_, (void*)(&Ws[sel][0] + (wv_ * 4 + i) * 512));
    }
  };

  auto COMPUTE = [&](int sel) {
    #pragma unroll
    for (int kc = 0; kc < 4; ++kc) {
      const int slot = (kc * 2 + lk2) ^ (l31 & 7);
      bf16x8 af[2], bx[2];
      #pragma unroll
      for (int fm = 0; fm < 2; ++fm)
        af[fm] = *(const bf16x8*)&Ws[sel][(wm * 64 + fm * 32 + l31) * 64 + slot * 8];
      #pragma unroll
      for (int fn = 0; fn < 2; ++fn)
        bx[fn] = *(const bf16x8*)&Xs[sel][(wn * 64 + fn * 32 + l31) * 64 + slot * 8];
      #pragma unroll
      for (int fm = 0; fm < 2; ++fm)
        #pragma unroll
        for (int fn = 0; fn < 2; ++fn)
          acc[fm][fn] = __builtin_amdgcn_mfma_f32_32x32x16_bf16(
              af[fm], bx[fn], acc[fm][fn], 0, 0, 0);
    }
  };

  STAGE(0, 0);
  __syncthreads();
  for (int base = 0; base < NIT; base += 2) {
    if (base + 1 < NIT) STAGE(base + 1, 1);
    COMPUTE(0);
    __syncthreads();
    if (base + 2 < NIT) STAGE(base + 2, 0);
    COMPUTE(1);
    __syncthreads();
  }

  // C layout (32x32): col=lane&31 (n), row=(reg&3)+8*(reg>>2)+4*(lane>>5) (co)
  #pragma unroll
  for (int fn = 0; fn < 2; ++fn) {
    int n = nt * 128 + wn * 64 + fn * 32 + l31;
    if (which == 0) {
      #pragma unroll
      for (int fm = 0; fm < 2; ++fm) {
        int cob = cobase + wm * 64 + fm * 32 + lk2 * 4;
        #pragma unroll
        for (int rg = 0; rg < 4; ++rg) {
          ushort4 pk;
          pk.x = f2b(acc[fm][fn][rg * 4 + 0]);
          pk.y = f2b(acc[fm][fn][rg * 4 + 1]);
          pk.z = f2b(acc[fm][fn][rg * 4 + 2]);
          pk.w = f2b(acc[fm][fn][rg * 4 + 3]);
          *(ushort4*)&outp[(size_t)n * C_N + cob + rg * 8] = pk;
        }
      }
    } else {
      int bf = n / HW_N, s = n - (n / HW_N) * HW_N;
      int b = bf >> 2, f = bf & 3;
      #pragma unroll
      for (int fm = 0; fm < 2; ++fm) {
        int cob = cobase + wm * 64 + fm * 32 + lk2 * 4;
        #pragma unroll
        for (int rg = 0; rg < 4; ++rg)
          #pragma unroll
          for (int j = 0; j < 4; ++j) {
            int co = cob + rg * 8 + j;
            outp[((size_t)(b * C_N + co)) * PL + (size_t)f * HW_N + s] =
                f2b(acc[fm][fn][rg * 4 + j]);
          }
      }
    }
  }
}

// ---------------- dual-output conv311: k and v1 share X staging ------------
// XCD-affine: 1D grid 392; xcd=bid&7 -> cot=xcd>>1, nt=(bid>>3)*2+(xcd&1).
__global__ __launch_bounds__(256, 2) void conv311_dual(
    const u16* __restrict__ xin, const u16* __restrict__ wa,
    const u16* __restrict__ wc, u16* __restrict__ outa,
    u16* __restrict__ outc, const u16* __restrict__ zbuf)
{
  const int bid = blockIdx.x;      // 392
  const int xcd = bid & 7;
  const int cot = xcd >> 1;
  const int nt = (bid >> 3) * 2 + (xcd & 1);   // 0..97
  const int cobase = cot << 7;
  const int t = threadIdx.x;
  const int wv = t >> 6, l = t & 63;
  const int wm = wv >> 1, wn = wv & 1;
  const int l31 = l & 31, lk2 = l >> 5;

  __shared__ u16 Xs[128 * 64];
  __shared__ u16 Was[128 * 64];
  __shared__ u16 Wcs[128 * 64];

  const int crow = l >> 3;
  const int chunk = (l & 7) ^ (crow & 7);

  int gcol[4], sf[4];
  #pragma unroll
  for (int i = 0; i < 4; ++i) {
    gcol[i] = nt * 128 + wv * 32 + i * 8 + crow;
    sf[i] = (gcol[i] / HW_N) & 3;
  }

  f32x16 acca[2][2], accc[2][2];
  #pragma unroll
  for (int fm = 0; fm < 2; ++fm)
    #pragma unroll
    for (int fn = 0; fn < 2; ++fn)
      #pragma unroll
      for (int e = 0; e < 16; ++e) { acca[fm][fn][e] = 0.f; accc[fm][fn][e] = 0.f; }

  for (int tap = 0; tap < 3; ++tap) {
    const u16* xp[4];
    const u16* wpa[4];
    const u16* wpc[4];
    int off = (tap - 1) * HW_N;
    #pragma unroll
    for (int i = 0; i < 4; ++i) {
      int ff = sf[i] + tap - 1;
      bool valid = ((unsigned)ff < 4u);
      xp[i] = valid ? (xin + (size_t)(gcol[i] + off) * C_N + chunk * 8)
                    : (zbuf + chunk * 8);
      int co = cobase + wv * 32 + i * 8 + crow;
      wpa[i] = wa + ((size_t)tap * C_N + co) * C_N + chunk * 8;
      wpc[i] = wc + ((size_t)tap * C_N + co) * C_N + chunk * 8;
    }
    for (int kb = 0; kb < 8; ++kb) {
      __syncthreads();
      #pragma unroll
      for (int i = 0; i < 4; ++i) {
        gl_lds16(xp[i],  (void*)(Xs  + (wv * 4 + i) * 512));
        gl_lds16(wpa[i], (void*)(Was + (wv * 4 + i) * 512));
        gl_lds16(wpc[i], (void*)(Wcs + (wv * 4 + i) * 512));
        xp[i] += 64; wpa[i] += 64; wpc[i] += 64;
      }
      __syncthreads();
      #pragma unroll
      for (int kc = 0; kc < 4; ++kc) {
        const int slot = (kc * 2 + lk2) ^ (l31 & 7);
        bf16x8 afa[2], afc[2], bx[2];
        #pragma unroll
        for (int fm = 0; fm < 2; ++fm) {
          afa[fm] = *(const bf16x8*)&Was[(wm * 64 + fm * 32 + l31) * 64 + slot * 8];
          afc[fm] = *(const bf16x8*)&Wcs[(wm * 64 + fm * 32 + l31) * 64 + slot * 8];
        }
        #pragma unroll
        for (int fn = 0; fn < 2; ++fn)
          bx[fn] = *(const bf16x8*)&Xs[(wn * 64 + fn * 32 + l31) * 64 + slot * 8];
        #pragma unroll
        for (int fm = 0; fm < 2; ++fm)
          #pragma unroll
          for (int fn = 0; fn < 2; ++fn) {
            acca[fm][fn] = __builtin_amdgcn_mfma_f32_32x32x16_bf16(
                afa[fm], bx[fn], acca[fm][fn], 0, 0, 0);
            accc[fm][fn] = __builtin_amdgcn_mfma_f32_32x32x16_bf16(
                afc[fm], bx[fn], accc[fm][fn], 0, 0, 0);
          }
      }
    }
  }

  #pragma unroll
  for (int fn = 0; fn < 2; ++fn) {
    int n = nt * 128 + wn * 64 + fn * 32 + l31;
    #pragma unroll
    for (int fm = 0; fm < 2; ++fm) {
      int cob = cobase + wm * 64 + fm * 32 + lk2 * 4;
      #pragma unroll
      for (int rg = 0; rg < 4; ++rg) {
        ushort4 pa, pc;
        pa.x = f2b(acca[fm][fn][rg * 4 + 0]); pa.y = f2b(acca[fm][fn][rg * 4 + 1]);
        pa.z = f2b(acca[fm][fn][rg * 4 + 2]); pa.w = f2b(acca[fm][fn][rg * 4 + 3]);
        pc.x = f2b(accc[fm][fn][rg * 4 + 0]); pc.y = f2b(accc[fm][fn][rg * 4 + 1]);
        pc.z = f2b(accc[fm][fn][rg * 4 + 2]); pc.w = f2b(accc[fm][fn][rg * 4 + 3]);
        *(ushort4*)&outa[(size_t)n * C_N + cob + rg * 8] = pa;
        *(ushort4*)&outc[(size_t)n * C_N + cob + rg * 8] = pc;
      }
    }
  }
}

// ---------------- MFMA fused attention (fixed-shift softmax, K/V dbuf) -----
__global__ __launch_bounds__(256, 2) void attn_mfma(
    const u16* __restrict__ q0, const u16* __restrict__ k0,
    const u16* __restrict__ v0,
    const float* __restrict__ rel_h, const float* __restrict__ rel_w,
    const float* __restrict__ rel_t, const float* __restrict__ rel_h2,
    const float* __restrict__ rel_w2, const float* __restrict__ rel_t2,
    float* __restrict__ out)
{
  // XCD-affine decode: all 7 q-tiles of a group land on one XCD (bid%8 const)
  const int bid = blockIdx.x;            // 896
  const int xcd = bid & 7, r = bid >> 3;
  const int gi = r / 7, qt = r - gi * 7;
  const int g = gi * 8 + xcd;
  const int b = g >> 5, gg = g & 31;
  const int cbase = gg << 4, h = gg >> 2, fgrp = gg & 3;
  const int qbase = min(qt * 128, 656);
  const int t = threadIdx.x;
  const int w = t >> 6, lane = t & 63, ll = lane & 15, lh = lane >> 4;

  __shared__ __align__(16) u16 smem[32768];        // 64 KB
  // Bp[2][64][128] @0, Vt[2][64][64] @16384, Pm[128][64] @24576
  u16* Pm = smem + 24576;
  float* Obuf = (float*)smem;                      // [64 e][130 q] (epilogue)

  const size_t slab = ((size_t)b * C_N + cbase) * PL;

  // A-operand in registers: Qt (global) + P (rel sums), k-tile invariant
  bf16x8 afr[2][4];
  #pragma unroll
  for (int mf = 0; mf < 2; ++mf) {
    const int q = qbase + w * 32 + mf * 16 + ll;
    const int y = q / 28, x = q - (q / 28) * 28;
    #pragma unroll
    for (int kk = 0; kk < 2; ++kk) {
      int c = kk * 4 + lh;
      afr[mf][kk] = *(const bf16x8*)&q0[((size_t)((b * 4 + (c >> 1)) * HW_N + q)) * C_N
                                        + cbase + (c & 1) * 8];
    }
    #pragma unroll
    for (int kk = 0; kk < 2; ++kk) {
      int ebase = kk * 32 + lh * 8;
      bf16x8 pv;
      #pragma unroll
      for (int j = 0; j < 8; ++j) {
        int e = ebase + j;
        int di = (e & 15) * 4 + (e >> 4);
        int idx = h * 64 + di;
        pv[j] = (short)f2b(rel_h[idx * 28 + y] + rel_w[idx * 28 + x]
                           + rel_t[idx * 4 + fgrp]);
      }
      afr[mf][2 + kk] = pv;
    }
  }

  f32x4 oacc[2][4];
  float l_[2][4];
  #pragma unroll
  for (int mf = 0; mf < 2; ++mf)
    #pragma unroll
    for (int nf = 0; nf < 4; ++nf) oacc[mf][nf] = (f32x4){0.f, 0.f, 0.f, 0.f};
  #pragma unroll
  for (int mf = 0; mf < 2; ++mf)
    #pragma unroll
    for (int r2 = 0; r2 < 4; ++r2) l_[mf][r2] = 0.f;

  auto STAGE = [&](int kt, int sel) {
    const int kbase = kt * 64;
    #pragma unroll
    for (int i = 0; i < 4; ++i) {
      int krow = w * 16 + i * 4 + lh;
      int c = (ll & 8) | ((ll ^ krow) & 7);
      int cc = c & 7;
      const u16* bsrc = (c < 8) ? k0 : q0;
      const u16* src = bsrc + ((size_t)((b * 4 + (cc >> 1)) * HW_N + kbase + krow)) * C_N
                       + cbase + (cc & 1) * 8;
      gl_lds16(src, (void*)(smem + sel * 8192 + (w * 16 + i * 4) * 128));
    }
    #pragma unroll
    for (int i = 0; i < 2; ++i) {
      int e = w * 16 + i * 8 + (lane >> 3);
      int ch = (lane & 7) ^ (e & 7);
      int di = (e & 15) * 4 + (e >> 4);
      const u16* src = v0 + slab + (size_t)di * HW_N + kbase + ch * 8;
      gl_lds16(src, (void*)(smem + 16384 + sel * 4096 + (w * 16 + i * 8) * 64));
    }
  };

  // p = exp(S/8 - 8) = 2^(S*0.1803369 - 11.5415603); shift-invariant softmax,
  // statistically safe: S ~ N(0, ~2.8), overflow needs S > ~770.
  const float C1 = 0.18033688f;
  const float C2 = -11.5415603f;

  STAGE(0, 0);
  __syncthreads();

  for (int kt = 0; kt < 13; ++kt) {
    const int cur = kt & 1;
    if (kt < 12) STAGE(kt + 1, cur ^ 1);
    const int kbase = kt * 64;
    const u16* BpC = smem + cur * 8192;
    const u16* VtC = smem + 16384 + cur * 4096;

    f32x4 sacc[2][4];
    #pragma unroll
    for (int mf = 0; mf < 2; ++mf)
      #pragma unroll
      for (int nf = 0; nf < 4; ++nf) sacc[mf][nf] = (f32x4){0.f, 0.f, 0.f, 0.f};
    #pragma unroll
    for (int kk = 0; kk < 4; ++kk) {
      bf16x8 bx[4];
      #pragma unroll
      for (int nf = 0; nf < 4; ++nf) {
        int slot = (kk * 4 + lh) ^ (ll & 7);
        bx[nf] = *(const bf16x8*)&BpC[(nf * 16 + ll) * 128 + slot * 8];
      }
      #pragma unroll
      for (int mf = 0; mf < 2; ++mf)
        #pragma unroll
        for (int nf = 0; nf < 4; ++nf)
          sacc[mf][nf] = __builtin_amdgcn_mfma_f32_16x16x32_bf16(
              afr[mf][kk], bx[nf], sacc[mf][nf], 0, 0, 0);
    }

    bool kval[4];
    #pragma unroll
    for (int nf = 0; nf < 4; ++nf) kval[nf] = (kbase + nf * 16 + ll) < HW_N;
    #pragma unroll
    for (int mf = 0; mf < 2; ++mf) {
      const int qlb = w * 32 + mf * 16;
      #pragma unroll
      for (int r2 = 0; r2 < 4; ++r2) {
        float p0 = __builtin_amdgcn_exp2f(fmaf(sacc[mf][0][r2], C1, C2));
        float p1 = __builtin_amdgcn_exp2f(fmaf(sacc[mf][1][r2], C1, C2));
        float p2 = __builtin_amdgcn_exp2f(fmaf(sacc[mf][2][r2], C1, C2));
        float p3 = __builtin_amdgcn_exp2f(fmaf(sacc[mf][3][r2], C1, C2));
        if (!kval[0]) p0 = 0.f;
        if (!kval[1]) p1 = 0.f;
        if (!kval[2]) p2 = 0.f;
        if (!kval[3]) p3 = 0.f;
        float psum = (p0 + p1) + (p2 + p3);
        #pragma unroll
        for (int off = 8; off >= 1; off >>= 1)
          psum += __shfl_xor(psum, off);
        l_[mf][r2] += psum;
        const int ql = qlb + lh * 4 + r2;
        const int swz = (ql & 7);
        Pm[ql * 64 + ((((ll >> 3))     ^ swz) * 8) + (ll & 7)] = f2b(p0);
        Pm[ql * 64 + (((2 + (ll >> 3)) ^ swz) * 8) + (ll & 7)] = f2b(p1);
        Pm[ql * 64 + (((4 + (ll >> 3)) ^ swz) * 8) + (ll & 7)] = f2b(p2);
        Pm[ql * 64 + (((6 + (ll >> 3)) ^ swz) * 8) + (ll & 7)] = f2b(p3);
      }
    }
    // Pm rows written+read by the SAME wave -> no barrier needed.

    #pragma unroll
    for (int ks = 0; ks < 2; ++ks) {
      bf16x8 pa[2], vb[4];
      #pragma unroll
      for (int mf = 0; mf < 2; ++mf) {
        int ql = w * 32 + mf * 16 + ll;
        int slot = (ks * 4 + lh) ^ (ql & 7);
        pa[mf] = *(const bf16x8*)&Pm[ql * 64 + slot * 8];
      }
      #pragma unroll
      for (int nf = 0; nf < 4; ++nf) {
        int e = nf * 16 + ll;
        int slot = (ks * 4 + lh) ^ (e & 7);
        vb[nf] = *(const bf16x8*)&VtC[e * 64 + slot * 8];
      }
      #pragma unroll
      for (int mf = 0; mf < 2; ++mf)
        #pragma unroll
        for (int nf = 0; nf < 4; ++nf)
          oacc[mf][nf] = __builtin_amdgcn_mfma_f32_16x16x32_bf16(
              pa[mf], vb[nf], oacc[mf][nf], 0, 0, 0);
    }
    __syncthreads();   // drains stage(kt+1); buf (kt-1)%2 safe to rewrite
  }

  float rinv[2][4];
  #pragma unroll
  for (int mf = 0; mf < 2; ++mf)
    #pragma unroll
    for (int r2 = 0; r2 < 4; ++r2) rinv[mf][r2] = 1.f / l_[mf][r2];
  #pragma unroll
  for (int mf = 0; mf < 2; ++mf)
    #pragma unroll
    for (int nf = 0; nf < 4; ++nf)
      #pragma unroll
      for (int r2 = 0; r2 < 4; ++r2)
        Obuf[(nf * 16 + ll) * 130 + w * 32 + mf * 16 + lh * 4 + r2] =
            oacc[mf][nf][r2] * rinv[mf][r2];
  __syncthreads();
  #pragma unroll 4
  for (int j = 0; j < 32; ++j) {
    int idx = t + 256 * j;
    int e = idx >> 7, ql = idx & 127;
    int s = qbase + ql;
    int c = cbase + (e & 15), fr = e >> 4;
    int y = s / 28, x = s - (s / 28) * 28;
    out[(((size_t)(b * C_N + c)) * 4 + fr) * HW_N + s] =
        Obuf[e * 130 + ql] + rel_t2[c * 4 + fr] + rel_h2[c * 28 + y]
        + rel_w2[c * 28 + x];
  }
}

extern "C" void kernel_launch(void* const* d_in, const int* in_sizes, int n_in,
                              void* d_out, int out_size, void* d_ws, size_t ws_size,
                              hipStream_t stream) {
  const float* x     = (const float*)d_in[0];
  const float* Wq    = (const float*)d_in[1];
  const float* Wk    = (const float*)d_in[2];
  const float* Wv1   = (const float*)d_in[3];
  const float* Wv2   = (const float*)d_in[4];
  const float* relh  = (const float*)d_in[5];
  const float* relw  = (const float*)d_in[6];
  const float* relt  = (const float*)d_in[7];
  const float* relh2 = (const float*)d_in[8];
  const float* relw2 = (const float*)d_in[9];
  const float* relt2 = (const float*)d_in[10];
  float* out = (float*)d_out;
  char* ws = (char*)d_ws;

  const size_t NE = (size_t)NTOT * C_N;    // 6,422,528 elements
  u16* xt   = (u16*)(ws);                  // x channels-last
  u16* q0   = (u16*)(ws + NE * 2);         // q channels-last
  u16* t0   = (u16*)(ws + NE * 4);         // v1 = conv311(x, Wv1) channels-last
  u16* k0   = (u16*)(ws + NE * 6);         // k channels-last
  u16* v0   = (u16*)(ws + NE * 8);         // v planar
  u16* wqb  = (u16*)(ws + NE * 10);
  u16* wkb  = (u16*)(ws + NE * 10 + 4718592);
  u16* wv1b = (u16*)(ws + NE * 10 + 4718592 + 1572864);
  u16* wv2b = (u16*)(ws + NE * 10 + 4718592 + 2 * 1572864);
  u16* zbuf = (u16*)(ws + NE * 10 + 2 * 4718592 + 2 * 1572864);  // 4 KB zeros

  zerok<<<dim3(4), dim3(256), 0, stream>>>((float*)zbuf);
  pack_all<<<dim3(24576), dim3(256), 0, stream>>>(
      Wq, Wk, Wv1, Wv2, wqb, wkb, wv1b, wv2b);
  cast_transpose<<<dim3(16, 13, 8), dim3(256), 0, stream>>>(x, xt);

  dim3 blk(256);
  // k = conv311(x, Wk), v1 = conv311(x, Wv1) — XCD-affine 1D grid
  conv311_dual<<<dim3(392), blk, 0, stream>>>(xt, wkb, wv1b, k0, t0, zbuf);
  // q = conv133(x, Wq), v = conv133(v1, Wv2) — XCD-affine 1D grid
  conv133_qv<<<dim3(784), blk, 0, stream>>>(xt, t0, wqb, wv2b, q0, v0, zbuf);

  attn_mfma<<<dim3(896), blk, 0, stream>>>(
      q0, k0, v0, relh, relw, relt, relh2, relw2, relt2, out);
}